// Round 5
// baseline (661.227 us; speedup 1.0000x reference)
//
#include <hip/hip_runtime.h>

#define HG 256
#define WGD 256
#define NN (HG*WGD)
#define NL 6

typedef _Float16 f16;
typedef _Float16 f16x8 __attribute__((ext_vector_type(8)));
typedef float f32x4 __attribute__((ext_vector_type(4)));

__device__ __forceinline__ void gload_lds16(const f16* g, f16* lds) {
  __builtin_amdgcn_global_load_lds(
      (const __attribute__((address_space(1))) unsigned int*)g,
      (__attribute__((address_space(3))) unsigned int*)lds, 16, 0, 0);
}

// C[M,N] = A[M,KK] @ Bt[N,KK]^T  (f16 in, f32 accum, f16 out), z-batched.
// LDS XOR-swizzled (T2), staged via pre-swizzled global source.
// EPI: 0 plain | 2 +bias[col]
template<int KK, int EPI>
__global__ __launch_bounds__(256) void gemm_bt(
    const f16* __restrict__ A, int lda, size_t asb,
    const f16* __restrict__ Bt, int ldb, size_t bsb,
    f16* __restrict__ C, int ldc, size_t csb,
    const float* __restrict__ bias)
{
  A  += blockIdx.z * asb;
  Bt += blockIdx.z * bsb;
  C  += blockIdx.z * csb;

  __shared__ f16 As[128*64];
  __shared__ f16 Bs[128*64];
  const int tid  = threadIdx.x;
  const int lane = tid & 63;
  const int w    = tid >> 6;
  const int wm   = w >> 1, wn = w & 1;
  const int mbase = blockIdx.x * 128;
  const int nbase = blockIdx.y * 128;

  f32x4 acc[4][4];
#pragma unroll
  for (int a=0;a<4;a++)
#pragma unroll
    for (int b=0;b<4;b++) acc[a][b] = (f32x4){0.f,0.f,0.f,0.f};

  const int r8  = lane >> 3;
  const int c8s = ((lane & 7) ^ r8) * 8;

  for (int kt = 0; kt < KK/64; ++kt) {
    const f16* Ab = A  + (size_t)(mbase + w*32)*lda + kt*64;
    const f16* Bb = Bt + (size_t)(nbase + w*32)*ldb + kt*64;
#pragma unroll
    for (int i=0;i<4;i++) {
      gload_lds16(Ab + (size_t)(i*8 + r8)*lda + c8s, &As[(w*32+i*8)*64]);
      gload_lds16(Bb + (size_t)(i*8 + r8)*ldb + c8s, &Bs[(w*32+i*8)*64]);
    }
    __syncthreads();
#pragma unroll
    for (int ks=0; ks<2; ++ks) {
      const int off = (((ks*4 + (lane>>4)) ^ (lane & 7)) * 8);
      f16x8 af[4], bf[4];
#pragma unroll
      for (int fm=0; fm<4; ++fm)
        af[fm] = *(const f16x8*)&As[(wm*64 + fm*16 + (lane&15))*64 + off];
#pragma unroll
      for (int fn=0; fn<4; ++fn)
        bf[fn] = *(const f16x8*)&Bs[(wn*64 + fn*16 + (lane&15))*64 + off];
#pragma unroll
      for (int fm=0; fm<4; ++fm)
#pragma unroll
        for (int fn=0; fn<4; ++fn)
          acc[fm][fn] = __builtin_amdgcn_mfma_f32_16x16x32_f16(af[fm], bf[fn], acc[fm][fn], 0,0,0);
    }
    __syncthreads();
  }

  const int row0 = mbase + wm*64 + (lane>>4)*4;
  const int col0 = nbase + wn*64 + (lane&15);
#pragma unroll
  for (int fm=0; fm<4; ++fm) {
#pragma unroll
    for (int fn=0; fn<4; ++fn) {
      const int col = col0 + fn*16;
#pragma unroll
      for (int r=0;r<4;r++) {
        int row = row0 + fm*16 + r;
        float v = acc[fm][fn][r];
        if (EPI==2) v += bias[col];
        C[(size_t)row*ldc + col] = (f16)v;
      }
    }
  }
}

// FUSED update: U' = relu([U | R] @ BtU^T + ubias + deg*v2 (+ g*avec if L1)).
// R (the K-chunks 4..7, or 0..3 for L1) is COMPUTED in-kernel from PQ
// (or analytically from g for L1) and ds_written into the swizzled As tile.
// 512 threads = 8 waves (2x4), output tile 128x256, U in/out [N][256].
template<int L1>
__global__ __launch_bounds__(512) void fused_upd(
    const f16* __restrict__ U,      // [N][256] (unused for L1)
    const f16* __restrict__ PQ,     // [N][512] (unused for L1)
    const f16* __restrict__ Bt,     // [256][K] slice, ldb 512
    f16* __restrict__ Uo,           // [N][256]
    const float* __restrict__ cvec, const float* __restrict__ wsi_,
    const float* __restrict__ wsj_,
    const float* __restrict__ ubias, const float* __restrict__ v2,
    const float* __restrict__ avec, const int* __restrict__ gridv,
    const float* __restrict__ pa,   const float* __restrict__ pc)
{
  constexpr int KK = L1 ? 256 : 512;
  __shared__ f16 As[128*64];
  __shared__ f16 Bs[256*64];
  const int tid  = threadIdx.x;
  const int lane = tid & 63;
  const int w    = tid >> 6;            // 0..7
  const int wm   = w >> 2, wn = w & 3;
  const int mbase = blockIdx.x * 128;

  f32x4 acc[4][4];
#pragma unroll
  for (int a=0;a<4;a++)
#pragma unroll
    for (int b=0;b<4;b++) acc[a][b] = (f32x4){0.f,0.f,0.f,0.f};

  const int r8  = lane >> 3;
  const int c8s = ((lane & 7) ^ r8) * 8;
  const int DI[4] = {-1,1,0,0};
  const int DJ[4] = {0,0,-1,1};

  for (int kt = 0; kt < KK/64; ++kt) {
    const int rchunk = L1 ? kt : kt - 4;
    // Bs: all 8 waves stage 32 rows each (rows w*32 + i*8 + r8)
    {
      const f16* Bb = Bt + (size_t)(w*32)*512 + kt*64;
#pragma unroll
      for (int i=0;i<4;i++)
        gload_lds16(Bb + (size_t)(i*8 + r8)*512 + c8s, &Bs[(w*32+i*8)*64]);
    }
    if (rchunk < 0) {
      // As from U global: waves 0..3
      if (w < 4) {
        const f16* Ab = U + (size_t)(mbase + w*32)*256 + kt*64;
#pragma unroll
        for (int i=0;i<4;i++)
          gload_lds16(Ab + (size_t)(i*8 + r8)*256 + c8s, &As[(w*32+i*8)*64]);
      }
    } else {
      // compute R chunk (128 rows x 64 cols) -> swizzled As
#pragma unroll
      for (int rep=0; rep<2; ++rep) {
        const int s  = rep*512 + tid;      // 0..1023
        const int r  = s >> 3;             // 0..127
        const int cg = s & 7;
        const int c0 = rchunk*64 + cg*8;   // R col 0..255
        const int n  = mbase + r;
        const int gi = n >> 8, gj = n & 255;
        float a8[8];
#pragma unroll
        for (int e=0;e<8;e++) a8[e] = 0.f;
        float q[8], pa0[8], pc0[8];
        if (L1) {
          float g = (float)gridv[n];
#pragma unroll
          for (int e=0;e<8;e++) {
            pa0[e] = pa[c0+e]; pc0[e] = pc[c0+e];
            q[e] = g*pa[256+c0+e] + pc[256+c0+e];
          }
        } else {
          f16x8 qv = *(const f16x8*)&PQ[(size_t)n*512 + 256 + c0];
#pragma unroll
          for (int e=0;e<8;e++) q[e] = (float)qv[e];
        }
#pragma unroll
        for (int d=0; d<4; ++d) {
          int si = gi - DI[d], sj = gj - DJ[d];
          if (si>=0 && si<HG && sj>=0 && sj<WGD) {
            int sn = si*WGD + sj;
            float fsi = si * (1.f/HG), fsj = sj * (1.f/WGD);
            float pvf[8];
            if (L1) {
              float gs = (float)gridv[sn];
#pragma unroll
              for (int e=0;e<8;e++) pvf[e] = gs*pa0[e] + pc0[e];
            } else {
              f16x8 pv = *(const f16x8*)&PQ[(size_t)sn*512 + c0];
#pragma unroll
              for (int e=0;e<8;e++) pvf[e] = (float)pv[e];
            }
#pragma unroll
            for (int e=0;e<8;e++) {
              float v = pvf[e] + q[e] + cvec[d*256+c0+e] + fsi*wsi_[c0+e] + fsj*wsj_[c0+e];
              a8[e] += fmaxf(v, 0.f);
            }
          }
        }
        f16x8 outv;
#pragma unroll
        for (int e=0;e<8;e++) outv[e] = (f16)a8[e];
        *(f16x8*)&As[r*64 + ((cg ^ (r & 7)) * 8)] = outv;
      }
    }
    __syncthreads();
#pragma unroll
    for (int ks=0; ks<2; ++ks) {
      const int off = (((ks*4 + (lane>>4)) ^ (lane & 7)) * 8);
      f16x8 af[4], bf[4];
#pragma unroll
      for (int fm=0; fm<4; ++fm)
        af[fm] = *(const f16x8*)&As[(wm*64 + fm*16 + (lane&15))*64 + off];
#pragma unroll
      for (int fn=0; fn<4; ++fn)
        bf[fn] = *(const f16x8*)&Bs[(wn*64 + fn*16 + (lane&15))*64 + off];
#pragma unroll
      for (int fm=0; fm<4; ++fm)
#pragma unroll
        for (int fn=0; fn<4; ++fn)
          acc[fm][fn] = __builtin_amdgcn_mfma_f32_16x16x32_f16(af[fm], bf[fn], acc[fm][fn], 0,0,0);
    }
    __syncthreads();
  }

  const int row0 = mbase + wm*64 + (lane>>4)*4;
  const int col0 = wn*64 + (lane&15);
#pragma unroll
  for (int fm=0; fm<4; ++fm) {
#pragma unroll
    for (int fn=0; fn<4; ++fn) {
      const int col = col0 + fn*16;
#pragma unroll
      for (int r=0;r<4;r++) {
        int row = row0 + fm*16 + r;
        int gi = row >> 8, gj = row & 255;
        float deg = (float)((gi>0)+(gi<255)+(gj>0)+(gj<255));
        float v = acc[fm][fn][r] + ubias[col] + deg * v2[col];
        if (L1) v += (float)gridv[row] * avec[col];
        v = fmaxf(v, 0.f);
        Uo[(size_t)row*256 + col] = (f16)v;
      }
    }
  }
}

// out[n,0..9] = U6[n,:] @ Wp2t^T + ob2  via MFMA, 1 wave = 16 nodes
__global__ __launch_bounds__(256) void out_mfma(
    const f16* __restrict__ U,        // [N][256]
    const f16* __restrict__ Wp2t,     // [128][256], rows >=10 zero
    const float* __restrict__ ob2,
    float* __restrict__ out)
{
  int lane = threadIdx.x & 63;
  int wv   = threadIdx.x >> 6;
  int nbase = blockIdx.x*64 + wv*16;
  f32x4 acc = (f32x4){0.f,0.f,0.f,0.f};
  int r  = lane & 15;
  int kg = (lane >> 4) * 8;
  const f16* Up = U + (size_t)(nbase + r)*256 + kg;
  const f16* Bp = Wp2t + r*256 + kg;
#pragma unroll
  for (int kt=0; kt<8; ++kt) {
    f16x8 af = *(const f16x8*)(Up + kt*32);
    f16x8 bf = *(const f16x8*)(Bp + kt*32);
    acc = __builtin_amdgcn_mfma_f32_16x16x32_f16(af, bf, acc, 0,0,0);
  }
  int col = lane & 15;
  int row0 = (lane>>4)*4;
  if (col < 10) {
    float bo = ob2[col];
#pragma unroll
    for (int rr=0; rr<4; ++rr)
      out[(size_t)(nbase + row0 + rr)*10 + col] = acc[rr] + bo;
  }
}

// ---- prep: LDS-tiled 256x256 transpose-cast, z-batched ----
__global__ __launch_bounds__(256) void tcast256(
    const float* __restrict__ src, size_t sls,
    f16* __restrict__ dst, size_t dls)
{
  __shared__ float tbuf[32][33];
  const int l = blockIdx.z;
  const int bc = blockIdx.x*32;
  const int br = blockIdx.y*32;
  const int tx = threadIdx.x & 31, ty = threadIdx.x >> 5;
  const float* s = src + (size_t)l*sls;
  f16* d = dst + (size_t)l*dls;
#pragma unroll
  for (int rr=0; rr<4; ++rr)
    tbuf[ty+rr*8][tx] = s[(size_t)(br+ty+rr*8)*256 + bc+tx];
  __syncthreads();
#pragma unroll
  for (int rr=0; rr<4; ++rr)
    d[(size_t)(bc+ty+rr*8)*256 + br+tx] = (f16)tbuf[tx][ty+rr*8];
}

__global__ __launch_bounds__(256) void castw(
    const float* __restrict__ uW2, const float* __restrict__ mW2,
    f16* __restrict__ uW2h, f16* __restrict__ mW2h)
{
  int idx = blockIdx.x*256+threadIdx.x;
  uW2h[idx] = (f16)uW2[idx];
  mW2h[idx] = (f16)mW2[idx];
}

__global__ __launch_bounds__(256) void prep_owt(const float* __restrict__ oW, f16* __restrict__ oWTh){
  int c = blockIdx.x, j = threadIdx.x;
  oWTh[c*256 + j] = (c < 10) ? (f16)oW[j*10 + c] : (f16)0.f;
}

__global__ __launch_bounds__(256) void prep_cw(
    const float* __restrict__ mW1, const float* __restrict__ mb1,
    float* __restrict__ cvec, float* __restrict__ wsi_, float* __restrict__ wsj_)
{
  int l = blockIdx.x, j = threadIdx.x;
  const float* base = mW1 + (size_t)l*516*256;
  float w512 = base[512*256 + j], w513 = base[513*256 + j];
  float b1 = mb1[l*256 + j];
  const int DI[4] = {-1,1,0,0};
  const int DJ[4] = {0,0,-1,1};
  for (int d=0;d<4;d++)
    cvec[(l*4+d)*256 + j] = (float)DI[d]*w512 + (float)DJ[d]*w513 + b1;
  wsi_[l*256+j] = base[514*256 + j];
  wsj_[l*256+j] = base[515*256 + j];
}

__global__ __launch_bounds__(256) void prep_vecB(
    const float* __restrict__ mb2, const float* __restrict__ uW1,
    const float* __restrict__ ub1, const float* __restrict__ ub2,
    const float* __restrict__ nb,  const float* __restrict__ nW,
    float* __restrict__ v2, float* __restrict__ ubias, float* __restrict__ avec)
{
  __shared__ float red[3][4][64];
  int pr = threadIdx.x & 63, q = threadIdx.x >> 6;
  int pair = blockIdx.x*64 + pr;
  int l = pair >> 8, j = pair & 255;
  const float* prevb = l ? (ub2 + (l-1)*256) : nb;
  float s1=0.f, s2=0.f, s3=0.f;
  for (int t = q*64; t < q*64+64; ++t) {
    s1 += mb2[l*256+t] * uW1[((size_t)l*512+256+t)*256 + j];
    s2 += prevb[t]     * uW1[((size_t)l*512+t)*256 + j];
    if (l==0) s3 += nW[t] * uW1[(size_t)t*256 + j];
  }
  red[0][q][pr]=s1; red[1][q][pr]=s2; red[2][q][pr]=s3;
  __syncthreads();
  if (q==0) {
    float a = red[0][0][pr]+red[0][1][pr]+red[0][2][pr]+red[0][3][pr];
    float b = red[1][0][pr]+red[1][1][pr]+red[1][2][pr]+red[1][3][pr];
    v2[pair] = a;
    ubias[pair] = ub1[pair] + b;
    if (l==0) avec[j] = red[2][0][pr]+red[2][1][pr]+red[2][2][pr]+red[2][3][pr];
  }
}

__global__ __launch_bounds__(256) void prep_pqb2(
    const float* __restrict__ mW1, const float* __restrict__ ub2,
    const float* __restrict__ nW,  const float* __restrict__ nb,
    float* __restrict__ pqb, float* __restrict__ pa, float* __restrict__ pc)
{
  __shared__ float red[2][4][64];
  int pr = threadIdx.x & 63, q = threadIdx.x >> 6;
  int pair = blockIdx.x*64 + pr;
  int l = pair >> 9, c = pair & 511;
  int rowoff = (c < 256) ? 0 : 256;
  int cc = c & 255;
  const float* base = mW1 + (size_t)l*516*256 + (size_t)rowoff*256 + cc;
  float s1=0.f, s2=0.f;
  if (l==0) {
    for (int j=q*64; j<q*64+64; ++j) { float wv = base[(size_t)j*256]; s1 += nW[j]*wv; s2 += nb[j]*wv; }
  } else {
    const float* pb = ub2 + (l-1)*256;
    for (int j=q*64; j<q*64+64; ++j) s1 += pb[j]*base[(size_t)j*256];
  }
  red[0][q][pr]=s1; red[1][q][pr]=s2;
  __syncthreads();
  if (q==0) {
    float a = red[0][0][pr]+red[0][1][pr]+red[0][2][pr]+red[0][3][pr];
    if (l==0) { pa[c]=a; pc[c]=red[1][0][pr]+red[1][1][pr]+red[1][2][pr]+red[1][3][pr]; }
    else pqb[pair] = a;
  }
}

__global__ __launch_bounds__(256) void prep_ob2(
    const float* __restrict__ ub2, const float* __restrict__ oW,
    const float* __restrict__ ob, float* __restrict__ ob2)
{
  __shared__ float red[16][16];
  int c = threadIdx.x >> 4, jg = threadIdx.x & 15;
  float s = 0.f;
  if (c < 10)
    for (int j=jg*16; j<jg*16+16; ++j) s += ub2[5*256+j]*oW[j*10+c];
  red[c][jg] = s;
  __syncthreads();
  if (jg==0) {
    float a=0.f;
    for (int t2=0;t2<16;t2++) a += red[c][t2];
    ob2[c] = (c < 10) ? a + ob[c] : 0.f;
  }
}

extern "C" void kernel_launch(void* const* d_in, const int* in_sizes, int n_in,
                              void* d_out, int out_size, void* d_ws, size_t ws_size,
                              hipStream_t stream)
{
  const int*   gridv = (const int*) d_in[0];
  const float* nW   = (const float*)d_in[3];
  const float* nb   = (const float*)d_in[4];
  const float* mW1  = (const float*)d_in[5];
  const float* mb1  = (const float*)d_in[6];
  const float* mW2  = (const float*)d_in[7];
  const float* mb2  = (const float*)d_in[8];
  const float* uW1  = (const float*)d_in[9];
  const float* ub1  = (const float*)d_in[10];
  const float* uW2  = (const float*)d_in[11];
  const float* ub2  = (const float*)d_in[12];
  const float* oW   = (const float*)d_in[13];
  const float* ob   = (const float*)d_in[14];
  float* out = (float*)d_out;

  char* ws = (char*)d_ws;
  size_t off = 0;
  f16* Ust  = (f16*)(ws + off); off += (size_t)NN*256*2;   // 32MB U state
  f16* PQ   = (f16*)(ws + off); off += (size_t)NN*512*2;   // 64MB
  f16* BtA  = (f16*)(ws + off); off += 6*512*256*2;
  f16* BtPQ = (f16*)(ws + off); off += 6*512*256*2;        // slot 0 unused
  f16* BtU  = (f16*)(ws + off); off += 6*256*512*2;
  f16* uW2h = (f16*)(ws + off); off += 6*256*256*2;
  f16* mW2h = (f16*)(ws + off); off += 6*256*256*2;
  f16* uW1aT= (f16*)(ws + off); off += 6*256*256*2;
  f16* uW1bT= (f16*)(ws + off); off += 6*256*256*2;
  f16* oWTh = (f16*)(ws + off); off += 128*256*2;
  f16* Wp2t = (f16*)(ws + off); off += 128*256*2;
  float* cvec = (float*)(ws + off); off += 6*4*256*4;
  float* wsi_ = (float*)(ws + off); off += 6*256*4;
  float* wsj_ = (float*)(ws + off); off += 6*256*4;
  float* v2   = (float*)(ws + off); off += 6*256*4;
  float* ubias= (float*)(ws + off); off += 6*256*4;
  float* pqb  = (float*)(ws + off); off += 6*512*4;        // slot 0 unused
  float* pa   = (float*)(ws + off); off += 512*4;
  float* pc   = (float*)(ws + off); off += 512*4;
  float* avec = (float*)(ws + off); off += 256*4;
  float* ob2  = (float*)(ws + off); off += 16*4;

  // ---- prep: casts & transposes ----
  tcast256<<<dim3(8,8,6),256,0,stream>>>(mW1,          516*256, BtA,          131072);
  tcast256<<<dim3(8,8,6),256,0,stream>>>(mW1 + 65536,  516*256, BtA + 65536,  131072);
  tcast256<<<dim3(8,8,6),256,0,stream>>>(uW1,          131072,  uW1aT,        65536);
  tcast256<<<dim3(8,8,6),256,0,stream>>>(uW1 + 65536,  131072,  uW1bT,        65536);
  castw   <<<1536,256,0,stream>>>(uW2, mW2, uW2h, mW2h);
  prep_owt<<<128, 256,0,stream>>>(oW, oWTh);
  prep_cw <<<6,   256,0,stream>>>(mW1, mb1, cvec, wsi_, wsj_);
  prep_vecB<<<24, 256,0,stream>>>(mb2, uW1, ub1, ub2, nb, nW, v2, ubias, avec);
  prep_pqb2<<<48, 256,0,stream>>>(mW1, ub2, nW, nb, pqb, pa, pc);
  prep_ob2<<<1,   256,0,stream>>>(ub2, oW, ob, ob2);

  // ---- prep: weight folds via MFMA ----
  gemm_bt<256,0><<<dim3(4,2,5),256,0,stream>>>(
      BtA + 131072, 256, 131072, uW2h, 256, 65536,
      BtPQ + 131072, 256, 131072, nullptr);
  gemm_bt<256,0><<<dim3(2,2,5),256,0,stream>>>(
      uW1aT + 65536, 256, 65536, uW2h, 256, 65536,
      BtU + 131072, 512, 131072, nullptr);
  gemm_bt<256,0><<<dim3(2,2,6),256,0,stream>>>(
      uW1bT, 256, 65536, mW2h, 256, 65536,
      BtU + 256, 512, 131072, nullptr);
  gemm_bt<256,0><<<dim3(1,2,1),256,0,stream>>>(
      oWTh, 256, 0, uW2h + 5*65536, 256, 0,
      Wp2t, 256, 0, nullptr);

  // ---- layer 1: fused (analytic P/Q from g, K=256 all-R) ----
  fused_upd<1><<<512,512,0,stream>>>(
      nullptr, nullptr, BtU + 256, Ust,
      cvec, wsi_, wsj_, ubias, v2, avec, gridv, pa, pc);

  // ---- layers 2..6 ----
  for (int l=1;l<NL;l++){
    // PQ_l = U_{l-1} @ BtPQ[l]^T + pqb[l]
    gemm_bt<256,2><<<dim3(512,4),256,0,stream>>>(
        Ust, 256, 0, BtPQ + (size_t)l*131072, 256, 0, PQ, 512, 0,
        pqb + l*512);
    // U_l = relu([U_{l-1} | R_l(PQ)] @ BtU[l]^T + ubias + deg*v2), in-place rows
    fused_upd<0><<<512,512,0,stream>>>(
        Ust, PQ, BtU + (size_t)l*131072, Ust,
        cvec + l*1024, wsi_ + l*256, wsj_ + l*256,
        ubias + l*256, v2 + l*256, nullptr, nullptr, nullptr, nullptr);
  }

  // out = U6 @ Wp2t^T + ob2
  out_mfma<<<1024,256,0,stream>>>(Ust, Wp2t, ob2, out);
}

// Round 6
// 576.415 us; speedup vs baseline: 1.1471x; 1.1471x over previous
//
#include <hip/hip_runtime.h>

#define HG 256
#define WGD 256
#define NN (HG*WGD)
#define NL 6

typedef _Float16 f16;
typedef _Float16 f16x8 __attribute__((ext_vector_type(8)));
typedef float f32x4 __attribute__((ext_vector_type(4)));

__device__ __forceinline__ void gload_lds16(const f16* g, f16* lds) {
  __builtin_amdgcn_global_load_lds(
      (const __attribute__((address_space(1))) unsigned int*)g,
      (__attribute__((address_space(3))) unsigned int*)lds, 16, 0, 0);
}

// C[M,N] = A[M,KK] @ Bt[N,KK]^T  (f16 in, f32 accum, f16 out), z-batched.
// LDS tiles XOR-swizzled (T2): 16B block b of row r lives at physical block
// b^(r&7). Staged via pre-swizzled GLOBAL source (LDS dest linear); read back
// with the same XOR (row&7 == lane&7 in the fragment read).
// EPI: 0 plain | 1 +bias[col]+deg(row)*v2[col], relu | 2 +bias[col]
//      3 +bias[col]+deg*v2[col]+g[row]*avec[col], relu   (layer-1 update)
template<int KK, int EPI>
__global__ __launch_bounds__(256) void gemm_bt(
    const f16* __restrict__ A, int lda, size_t asb,
    const f16* __restrict__ Bt, int ldb, size_t bsb,
    f16* __restrict__ C, int ldc, size_t csb,
    const float* __restrict__ bias,
    const float* __restrict__ v2,
    const float* __restrict__ avec,
    const int* __restrict__ gridv)
{
  A  += blockIdx.z * asb;
  Bt += blockIdx.z * bsb;
  C  += blockIdx.z * csb;

  __shared__ f16 As[128*64];
  __shared__ f16 Bs[128*64];
  const int tid  = threadIdx.x;
  const int lane = tid & 63;
  const int w    = tid >> 6;
  const int wm   = w >> 1, wn = w & 1;
  const int mbase = blockIdx.x * 128;
  const int nbase = blockIdx.y * 128;

  f32x4 acc[4][4];
#pragma unroll
  for (int a=0;a<4;a++)
#pragma unroll
    for (int b=0;b<4;b++) acc[a][b] = (f32x4){0.f,0.f,0.f,0.f};

  const int r8  = lane >> 3;
  const int c8s = ((lane & 7) ^ r8) * 8;

  for (int kt = 0; kt < KK/64; ++kt) {
    const f16* Ab = A  + (size_t)(mbase + w*32)*lda + kt*64;
    const f16* Bb = Bt + (size_t)(nbase + w*32)*ldb + kt*64;
#pragma unroll
    for (int i=0;i<4;i++) {
      gload_lds16(Ab + (size_t)(i*8 + r8)*lda + c8s, &As[(w*32+i*8)*64]);
      gload_lds16(Bb + (size_t)(i*8 + r8)*ldb + c8s, &Bs[(w*32+i*8)*64]);
    }
    __syncthreads();
#pragma unroll
    for (int ks=0; ks<2; ++ks) {
      const int off = (((ks*4 + (lane>>4)) ^ (lane & 7)) * 8);
      f16x8 af[4], bf[4];
#pragma unroll
      for (int fm=0; fm<4; ++fm)
        af[fm] = *(const f16x8*)&As[(wm*64 + fm*16 + (lane&15))*64 + off];
#pragma unroll
      for (int fn=0; fn<4; ++fn)
        bf[fn] = *(const f16x8*)&Bs[(wn*64 + fn*16 + (lane&15))*64 + off];
#pragma unroll
      for (int fm=0; fm<4; ++fm)
#pragma unroll
        for (int fn=0; fn<4; ++fn)
          acc[fm][fn] = __builtin_amdgcn_mfma_f32_16x16x32_f16(af[fm], bf[fn], acc[fm][fn], 0,0,0);
    }
    __syncthreads();
  }

  const int row0 = mbase + wm*64 + (lane>>4)*4;
  const int col0 = nbase + wn*64 + (lane&15);
#pragma unroll
  for (int fm=0; fm<4; ++fm) {
#pragma unroll
    for (int fn=0; fn<4; ++fn) {
      const int col = col0 + fn*16;
#pragma unroll
      for (int r=0;r<4;r++) {
        int row = row0 + fm*16 + r;
        float v = acc[fm][fn][r];
        if (EPI==1 || EPI==3) {
          int i = row >> 8, j = row & 255;
          float deg = (float)((i>0)+(i<255)+(j>0)+(j<255));
          v += bias[col] + deg * v2[col];
          if (EPI==3) v += (float)gridv[row] * avec[col];
          v = fmaxf(v, 0.f);
        } else if (EPI==2) {
          v += bias[col];
        }
        C[(size_t)row*ldc + col] = (f16)v;
      }
    }
  }
}

// R[n] = sum over valid dirs of relu(P[src]+Q[n]+cvec_d+(si/256)*wsi+(sj/256)*wsj)
// R1=0: PQ [N,512] cols 0..255 = P, 256..511 = Q.
// R1=1: P/Q analytic from g (rank-1 layer 1).
template<int R1>
__global__ __launch_bounds__(256) void edge_fuse(
    const f16* __restrict__ PQ, f16* __restrict__ UR,
    const float* __restrict__ cvec, const float* __restrict__ wsi_,
    const float* __restrict__ wsj_,
    const int* __restrict__ gridv, const float* __restrict__ pa,
    const float* __restrict__ pc)
{
  const int t  = threadIdx.x;
  const int ln = t >> 5, ch = t & 31;
  const int n  = blockIdx.x*8 + ln;
  const int i  = n >> 8, j = n & 255;
  const int co = ch*8;

  float q[8], pa0[8], pc0[8];
  if (R1) {
    float g = (float)gridv[n];
#pragma unroll
    for (int e=0;e<8;e++) {
      pa0[e] = pa[co+e]; pc0[e] = pc[co+e];
      q[e] = g*pa[256+co+e] + pc[256+co+e];
    }
  } else {
    f16x8 qv = *(const f16x8*)&PQ[(size_t)n*512 + 256 + co];
#pragma unroll
    for (int e=0;e<8;e++) q[e] = (float)qv[e];
  }
  float wi[8], wj[8];
#pragma unroll
  for (int e=0;e<8;e++){ wi[e]=wsi_[co+e]; wj[e]=wsj_[co+e]; }
  float acc[8];
#pragma unroll
  for (int e=0;e<8;e++) acc[e]=0.f;

  const int DI[4] = {-1,1,0,0};
  const int DJ[4] = {0,0,-1,1};
#pragma unroll
  for (int d=0; d<4; ++d) {
    int si = i - DI[d], sj = j - DJ[d];
    if (si>=0 && si<HG && sj>=0 && sj<WGD) {
      int s = si*WGD + sj;
      float fsi = si * (1.f/HG), fsj = sj * (1.f/WGD);
      float pvf[8];
      if (R1) {
        float gs = (float)gridv[s];
#pragma unroll
        for (int e=0;e<8;e++) pvf[e] = gs*pa0[e] + pc0[e];
      } else {
        f16x8 pv = *(const f16x8*)&PQ[(size_t)s*512 + co];
#pragma unroll
        for (int e=0;e<8;e++) pvf[e] = (float)pv[e];
      }
#pragma unroll
      for (int e=0;e<8;e++) {
        float v = pvf[e] + q[e] + cvec[d*256+co+e] + fsi*wi[e] + fsj*wj[e];
        acc[e] += fmaxf(v, 0.f);
      }
    }
  }
  f16x8 outv;
#pragma unroll
  for (int e=0;e<8;e++) outv[e] = (f16)acc[e];
  *(f16x8*)&UR[(size_t)n*512 + 256 + co] = outv;
}

// out[n,0..9] = U6[n,:] @ Wp2t^T + ob2  via MFMA, 1 wave = 16 nodes
__global__ __launch_bounds__(256) void out_mfma(
    const f16* __restrict__ U,        // lda 512
    const f16* __restrict__ Wp2t,     // [128][256], rows >=10 zero
    const float* __restrict__ ob2,
    float* __restrict__ out)
{
  int lane = threadIdx.x & 63;
  int wv   = threadIdx.x >> 6;
  int nbase = blockIdx.x*64 + wv*16;
  f32x4 acc = (f32x4){0.f,0.f,0.f,0.f};
  int r  = lane & 15;
  int kg = (lane >> 4) * 8;
  const f16* Up = U + (size_t)(nbase + r)*512 + kg;
  const f16* Bp = Wp2t + r*256 + kg;
#pragma unroll
  for (int kt=0; kt<8; ++kt) {
    f16x8 af = *(const f16x8*)(Up + kt*32);
    f16x8 bf = *(const f16x8*)(Bp + kt*32);
    acc = __builtin_amdgcn_mfma_f32_16x16x32_f16(af, bf, acc, 0,0,0);
  }
  int col = lane & 15;
  int row0 = (lane>>4)*4;
  if (col < 10) {
    float bo = ob2[col];
#pragma unroll
    for (int rr=0; rr<4; ++rr)
      out[(size_t)(nbase + row0 + rr)*10 + col] = acc[rr] + bo;
  }
}

// ---- prep: all 4 transpose-casts in ONE dispatch (z = q*6 + l) ----
// q0: W1a^T -> BtA rows 0..255 | q1: W1b^T -> BtA rows 256..511
// q2: uW1a^T -> uW1aT          | q3: uW1b^T -> uW1bT
__global__ __launch_bounds__(256) void tcast_all(
    const float* __restrict__ mW1, const float* __restrict__ uW1,
    f16* __restrict__ BtA, f16* __restrict__ uW1aT, f16* __restrict__ uW1bT)
{
  __shared__ float tbuf[32][33];
  const int z = blockIdx.z;
  const int q = z / 6, l = z % 6;
  const float* s;
  f16* d;
  if (q == 0)      { s = mW1 + (size_t)l*516*256;          d = BtA   + (size_t)l*131072; }
  else if (q == 1) { s = mW1 + (size_t)l*516*256 + 65536;  d = BtA   + (size_t)l*131072 + 65536; }
  else if (q == 2) { s = uW1 + (size_t)l*131072;           d = uW1aT + (size_t)l*65536; }
  else             { s = uW1 + (size_t)l*131072 + 65536;   d = uW1bT + (size_t)l*65536; }
  const int bc = blockIdx.x*32;
  const int br = blockIdx.y*32;
  const int tx = threadIdx.x & 31, ty = threadIdx.x >> 5;
#pragma unroll
  for (int rr=0; rr<4; ++rr)
    tbuf[ty+rr*8][tx] = s[(size_t)(br+ty+rr*8)*256 + bc+tx];
  __syncthreads();
#pragma unroll
  for (int rr=0; rr<4; ++rr)
    d[(size_t)(bc+ty+rr*8)*256 + br+tx] = (f16)tbuf[tx][ty+rr*8];
}

// ---- prep: casts + oW transpose + cvec/wsi/wsj, ONE dispatch ----
// blocks [0,1536): uW2h/mW2h casts; [1536,1664): oWTh; [1664,1670): cvec etc.
__global__ __launch_bounds__(256) void prep_misc(
    const float* __restrict__ uW2, const float* __restrict__ mW2,
    const float* __restrict__ oW,  const float* __restrict__ mW1,
    const float* __restrict__ mb1,
    f16* __restrict__ uW2h, f16* __restrict__ mW2h, f16* __restrict__ oWTh,
    float* __restrict__ cvec, float* __restrict__ wsi_, float* __restrict__ wsj_)
{
  const int b = blockIdx.x;
  const int tid = threadIdx.x;
  if (b < 1536) {
    int idx = b*256 + tid;
    uW2h[idx] = (f16)uW2[idx];
    mW2h[idx] = (f16)mW2[idx];
  } else if (b < 1664) {
    int c = b - 1536, j = tid;
    oWTh[c*256 + j] = (c < 10) ? (f16)oW[j*10 + c] : (f16)0.f;
  } else {
    int l = b - 1664, j = tid;
    const float* base = mW1 + (size_t)l*516*256;
    float w512 = base[512*256 + j], w513 = base[513*256 + j];
    float b1 = mb1[l*256 + j];
    const int DI[4] = {-1,1,0,0};
    const int DJ[4] = {0,0,-1,1};
    for (int d=0;d<4;d++)
      cvec[(l*4+d)*256 + j] = (float)DI[d]*w512 + (float)DJ[d]*w513 + b1;
    wsi_[l*256+j] = base[514*256 + j];
    wsj_[l*256+j] = base[515*256 + j];
  }
}

__global__ __launch_bounds__(256) void prep_vecB(
    const float* __restrict__ mb2, const float* __restrict__ uW1,
    const float* __restrict__ ub1, const float* __restrict__ ub2,
    const float* __restrict__ nb,  const float* __restrict__ nW,
    float* __restrict__ v2, float* __restrict__ ubias, float* __restrict__ avec)
{
  __shared__ float red[3][4][64];
  int pr = threadIdx.x & 63, q = threadIdx.x >> 6;
  int pair = blockIdx.x*64 + pr;
  int l = pair >> 8, j = pair & 255;
  const float* prevb = l ? (ub2 + (l-1)*256) : nb;
  float s1=0.f, s2=0.f, s3=0.f;
  for (int t = q*64; t < q*64+64; ++t) {
    s1 += mb2[l*256+t] * uW1[((size_t)l*512+256+t)*256 + j];
    s2 += prevb[t]     * uW1[((size_t)l*512+t)*256 + j];
    if (l==0) s3 += nW[t] * uW1[(size_t)t*256 + j];
  }
  red[0][q][pr]=s1; red[1][q][pr]=s2; red[2][q][pr]=s3;
  __syncthreads();
  if (q==0) {
    float a = red[0][0][pr]+red[0][1][pr]+red[0][2][pr]+red[0][3][pr];
    float b = red[1][0][pr]+red[1][1][pr]+red[1][2][pr]+red[1][3][pr];
    v2[pair] = a;
    ubias[pair] = ub1[pair] + b;
    if (l==0) avec[j] = red[2][0][pr]+red[2][1][pr]+red[2][2][pr]+red[2][3][pr];
  }
}

__global__ __launch_bounds__(256) void prep_pqb2(
    const float* __restrict__ mW1, const float* __restrict__ ub2,
    const float* __restrict__ nW,  const float* __restrict__ nb,
    float* __restrict__ pqb, float* __restrict__ pa, float* __restrict__ pc)
{
  __shared__ float red[2][4][64];
  int pr = threadIdx.x & 63, q = threadIdx.x >> 6;
  int pair = blockIdx.x*64 + pr;
  int l = pair >> 9, c = pair & 511;
  int rowoff = (c < 256) ? 0 : 256;
  int cc = c & 255;
  const float* base = mW1 + (size_t)l*516*256 + (size_t)rowoff*256 + cc;
  float s1=0.f, s2=0.f;
  if (l==0) {
    for (int j=q*64; j<q*64+64; ++j) { float wv = base[(size_t)j*256]; s1 += nW[j]*wv; s2 += nb[j]*wv; }
  } else {
    const float* pb = ub2 + (l-1)*256;
    for (int j=q*64; j<q*64+64; ++j) s1 += pb[j]*base[(size_t)j*256];
  }
  red[0][q][pr]=s1; red[1][q][pr]=s2;
  __syncthreads();
  if (q==0) {
    float a = red[0][0][pr]+red[0][1][pr]+red[0][2][pr]+red[0][3][pr];
    if (l==0) { pa[c]=a; pc[c]=red[1][0][pr]+red[1][1][pr]+red[1][2][pr]+red[1][3][pr]; }
    else pqb[pair] = a;
  }
}

__global__ __launch_bounds__(256) void prep_ob2(
    const float* __restrict__ ub2, const float* __restrict__ oW,
    const float* __restrict__ ob, float* __restrict__ ob2)
{
  __shared__ float red[16][16];
  int c = threadIdx.x >> 4, jg = threadIdx.x & 15;
  float s = 0.f;
  if (c < 10)
    for (int j=jg*16; j<jg*16+16; ++j) s += ub2[5*256+j]*oW[j*10+c];
  red[c][jg] = s;
  __syncthreads();
  if (jg==0) {
    float a=0.f;
    for (int t2=0;t2<16;t2++) a += red[c][t2];
    ob2[c] = (c < 10) ? a + ob[c] : 0.f;
  }
}

extern "C" void kernel_launch(void* const* d_in, const int* in_sizes, int n_in,
                              void* d_out, int out_size, void* d_ws, size_t ws_size,
                              hipStream_t stream)
{
  const int*   gridv = (const int*) d_in[0];
  const float* nW   = (const float*)d_in[3];
  const float* nb   = (const float*)d_in[4];
  const float* mW1  = (const float*)d_in[5];
  const float* mb1  = (const float*)d_in[6];
  const float* mW2  = (const float*)d_in[7];
  const float* mb2  = (const float*)d_in[8];
  const float* uW1  = (const float*)d_in[9];
  const float* ub1  = (const float*)d_in[10];
  const float* uW2  = (const float*)d_in[11];
  const float* ub2  = (const float*)d_in[12];
  const float* oW   = (const float*)d_in[13];
  const float* ob   = (const float*)d_in[14];
  float* out = (float*)d_out;

  char* ws = (char*)d_ws;
  size_t off = 0;
  f16* URa  = (f16*)(ws + off); off += (size_t)NN*512*2;
  f16* URb  = (f16*)(ws + off); off += (size_t)NN*512*2;
  f16* BtA  = (f16*)(ws + off); off += 6*512*256*2;
  f16* BtPQ = (f16*)(ws + off); off += 6*512*256*2;   // slot 0 unused
  f16* BtU  = (f16*)(ws + off); off += 6*256*512*2;
  f16* uW2h = (f16*)(ws + off); off += 6*256*256*2;
  f16* mW2h = (f16*)(ws + off); off += 6*256*256*2;
  f16* uW1aT= (f16*)(ws + off); off += 6*256*256*2;
  f16* uW1bT= (f16*)(ws + off); off += 6*256*256*2;
  f16* oWTh = (f16*)(ws + off); off += 128*256*2;
  f16* Wp2t = (f16*)(ws + off); off += 128*256*2;
  float* cvec = (float*)(ws + off); off += 6*4*256*4;
  float* wsi_ = (float*)(ws + off); off += 6*256*4;
  float* wsj_ = (float*)(ws + off); off += 6*256*4;
  float* v2   = (float*)(ws + off); off += 6*256*4;
  float* ubias= (float*)(ws + off); off += 6*256*4;
  float* pqb  = (float*)(ws + off); off += 6*512*4;   // slot 0 unused
  float* pa   = (float*)(ws + off); off += 512*4;
  float* pc   = (float*)(ws + off); off += 512*4;
  float* avec = (float*)(ws + off); off += 256*4;
  float* ob2  = (float*)(ws + off); off += 16*4;

  // ---- prep: merged casts/transposes + small vectors ----
  tcast_all<<<dim3(8,8,24),256,0,stream>>>(mW1, uW1, BtA, uW1aT, uW1bT);
  prep_misc<<<1670,256,0,stream>>>(uW2, mW2, oW, mW1, mb1,
                                   uW2h, mW2h, oWTh, cvec, wsi_, wsj_);
  prep_vecB<<<24, 256,0,stream>>>(mb2, uW1, ub1, ub2, nb, nW, v2, ubias, avec);
  prep_pqb2<<<48, 256,0,stream>>>(mW1, ub2, nW, nb, pqb, pa, pc);
  prep_ob2<<<1,   256,0,stream>>>(ub2, oW, ob, ob2);

  // ---- prep: weight folds via MFMA ----
  gemm_bt<256,0><<<dim3(4,2,5),256,0,stream>>>(
      BtA + 131072, 256, 131072, uW2h, 256, 65536,
      BtPQ + 131072, 256, 131072, nullptr, nullptr, nullptr, nullptr);
  gemm_bt<256,0><<<dim3(2,2,5),256,0,stream>>>(
      uW1aT + 65536, 256, 65536, uW2h, 256, 65536,
      BtU + 131072, 512, 131072, nullptr, nullptr, nullptr, nullptr);
  gemm_bt<256,0><<<dim3(2,2,6),256,0,stream>>>(
      uW1bT, 256, 65536, mW2h, 256, 65536,
      BtU + 256, 512, 131072, nullptr, nullptr, nullptr, nullptr);
  gemm_bt<256,0><<<dim3(1,2,1),256,0,stream>>>(
      oWTh, 256, 0, uW2h + 5*65536, 256, 0,
      Wp2t, 256, 0, nullptr, nullptr, nullptr, nullptr);

  // ---- layer 1 (rank-1 input, P/Q analytic) ----
  edge_fuse<1><<<8192,256,0,stream>>>(nullptr, URa, cvec, wsi_, wsj_, gridv, pa, pc);
  gemm_bt<256,3><<<dim3(512,2),256,0,stream>>>(
      URa + 256, 512, 0, BtU + 256, 512, 0, URa, 512, 0,
      ubias, v2, avec, gridv);

  // ---- layers 2..6 ----
  f16* cur = URa; f16* nxt = URb;
  for (int l=1;l<NL;l++){
    gemm_bt<256,2><<<dim3(512,4),256,0,stream>>>(
        cur, 512, 0, BtPQ + (size_t)l*131072, 256, 0, nxt, 512, 0,
        pqb + l*512, nullptr, nullptr, nullptr);
    edge_fuse<0><<<8192,256,0,stream>>>(nxt, cur, cvec + l*1024, wsi_ + l*256, wsj_ + l*256,
                                        nullptr, nullptr, nullptr);
    gemm_bt<512,1><<<dim3(512,2),256,0,stream>>>(
        cur, 512, 0, BtU + (size_t)l*131072, 512, 0, nxt, 512, 0,
        ubias + l*256, v2 + l*256, nullptr, nullptr);
    f16* t = cur; cur = nxt; nxt = t;
  }

  // out = U6 @ Wp2t^T + ob2
  out_mfma<<<1024,256,0,stream>>>(cur, Wp2t, ob2, out);
}

// Round 7
// 533.196 us; speedup vs baseline: 1.2401x; 1.0811x over previous
//
#include <hip/hip_runtime.h>

#define HG 256
#define WGD 256
#define NN (HG*WGD)
#define NL 6

typedef _Float16 f16;
typedef _Float16 f16x8 __attribute__((ext_vector_type(8)));
typedef float f32x4 __attribute__((ext_vector_type(4)));

__device__ __forceinline__ void gload_lds16(const f16* g, f16* lds) {
  __builtin_amdgcn_global_load_lds(
      (const __attribute__((address_space(1))) unsigned int*)g,
      (__attribute__((address_space(3))) unsigned int*)lds, 16, 0, 0);
}

// ---- 8-wave 128x256 GEMM, double-buffered LDS, 2-phase pipeline (T3-min) ----
// C[M,N] = A[M,KK] @ Bt[N,KK]^T, f16 in, f32 accum, f16 out. N = gridDim.y*256.
// LDS XOR-swizzled (T2): 16B block b of row r at physical b^(r&7); staged via
// pre-swizzled global source (LDS dest linear), read back with the same XOR.
// EPI: 1 +bias[col]+deg(row)*v2[col], relu | 2 +bias[col]
//      3 EPI1 + g[row]*avec[col] (layer-1 update)
template<int KK, int EPI>
__global__ __launch_bounds__(512) void gemm8(
    const f16* __restrict__ A, int lda,
    const f16* __restrict__ Bt, int ldb,
    f16* __restrict__ C, int ldc,
    const float* __restrict__ bias,
    const float* __restrict__ v2,
    const float* __restrict__ avec,
    const int* __restrict__ gridv)
{
  constexpr int NT = KK/64;
  __shared__ f16 As[2][128*64];   // 32 KB
  __shared__ f16 Bs[2][256*64];   // 64 KB
  const int tid  = threadIdx.x;
  const int lane = tid & 63;
  const int w    = tid >> 6;          // 0..7
  const int wm   = w >> 2, wn = w & 3;

  // bijective XCD swizzle (nwg % 8 == 0 for all our grids)
  int bid = blockIdx.y * gridDim.x + blockIdx.x;
  const int nwg = gridDim.x * gridDim.y;
  { int q = nwg >> 3; bid = (bid & 7) * q + (bid >> 3); }
  const int bx = bid % gridDim.x, by = bid / gridDim.x;
  const int mbase = bx * 128;
  const int nbase = by * 256;

  f32x4 acc[4][4];
#pragma unroll
  for (int a=0;a<4;a++)
#pragma unroll
    for (int b=0;b<4;b++) acc[a][b] = (f32x4){0.f,0.f,0.f,0.f};

  const int r8  = lane >> 3;                 // 0..7
  const int c8s = ((lane & 7) ^ r8) * 8;     // pre-swizzled src col (f16)

  // STAGE: wave-chunked; wave w, pass p covers LDS rows (p*8+w)*8 .. +8
#define STAGE8(kt, buf)                                                        \
  {                                                                            \
    const f16* Ab = A + (size_t)mbase*lda + (kt)*64;                           \
    _Pragma("unroll")                                                          \
    for (int p=0;p<2;p++) {                                                    \
      int qc = p*8 + w;                                                        \
      gload_lds16(Ab + (size_t)(qc*8 + r8)*lda + c8s, &As[buf][qc*512]);       \
    }                                                                          \
    const f16* Bb = Bt + (size_t)nbase*ldb + (kt)*64;                          \
    _Pragma("unroll")                                                          \
    for (int p=0;p<4;p++) {                                                    \
      int qc = p*8 + w;                                                        \
      gload_lds16(Bb + (size_t)(qc*8 + r8)*ldb + c8s, &Bs[buf][qc*512]);       \
    }                                                                          \
  }

  STAGE8(0, 0);
  __syncthreads();
  int cur = 0;
  for (int kt = 0; kt < NT; ++kt) {
    if (kt + 1 < NT) STAGE8(kt + 1, cur ^ 1);
    const f16* Acur = &As[cur][0];
    const f16* Bcur = &Bs[cur][0];
#pragma unroll
    for (int ks=0; ks<2; ++ks) {
      const int off = (((ks*4 + (lane>>4)) ^ (lane & 7)) * 8);
      f16x8 af[4], bf[4];
#pragma unroll
      for (int fm=0; fm<4; ++fm)
        af[fm] = *(const f16x8*)&Acur[(wm*64 + fm*16 + (lane&15))*64 + off];
#pragma unroll
      for (int fn=0; fn<4; ++fn)
        bf[fn] = *(const f16x8*)&Bcur[(wn*64 + fn*16 + (lane&15))*64 + off];
#pragma unroll
      for (int fm=0; fm<4; ++fm)
#pragma unroll
        for (int fn=0; fn<4; ++fn)
          acc[fm][fn] = __builtin_amdgcn_mfma_f32_16x16x32_f16(af[fm], bf[fn], acc[fm][fn], 0,0,0);
    }
    __syncthreads();   // drains this iter's STAGE (vmcnt) + ds_reads (lgkm)
    cur ^= 1;
  }
#undef STAGE8

  const int row0 = mbase + wm*64 + (lane>>4)*4;
  const int col0 = nbase + wn*64 + (lane&15);
#pragma unroll
  for (int fm=0; fm<4; ++fm) {
#pragma unroll
    for (int fn=0; fn<4; ++fn) {
      const int col = col0 + fn*16;
#pragma unroll
      for (int r=0;r<4;r++) {
        int row = row0 + fm*16 + r;
        float v = acc[fm][fn][r];
        if (EPI==1 || EPI==3) {
          int i = row >> 8, j = row & 255;
          float deg = (float)((i>0)+(i<255)+(j>0)+(j<255));
          v += bias[col & 255] + deg * v2[col & 255];
          if (EPI==3) v += (float)gridv[row] * avec[col & 255];
          v = fmaxf(v, 0.f);
        } else if (EPI==2) {
          v += bias[col];
        }
        C[(size_t)row*ldc + col] = (f16)v;
      }
    }
  }
}

// ---- 4-wave 128x128 GEMM core (K=256), used by the merged fold dispatch ----
__device__ __forceinline__ void gemm_core256(
    const f16* __restrict__ A, int lda,
    const f16* __restrict__ Bt, int ldb,
    f16* __restrict__ C, int ldc,
    int mbase, int nbase, f16* As, f16* Bs)
{
  const int tid  = threadIdx.x;
  const int lane = tid & 63;
  const int w    = tid >> 6;
  const int wm   = w >> 1, wn = w & 1;

  f32x4 acc[4][4];
#pragma unroll
  for (int a=0;a<4;a++)
#pragma unroll
    for (int b=0;b<4;b++) acc[a][b] = (f32x4){0.f,0.f,0.f,0.f};

  const int r8  = lane >> 3;
  const int c8s = ((lane & 7) ^ r8) * 8;

  for (int kt = 0; kt < 4; ++kt) {
    const f16* Ab = A  + (size_t)(mbase + w*32)*lda + kt*64;
    const f16* Bb = Bt + (size_t)(nbase + w*32)*ldb + kt*64;
#pragma unroll
    for (int i=0;i<4;i++) {
      gload_lds16(Ab + (size_t)(i*8 + r8)*lda + c8s, &As[(w*32+i*8)*64]);
      gload_lds16(Bb + (size_t)(i*8 + r8)*ldb + c8s, &Bs[(w*32+i*8)*64]);
    }
    __syncthreads();
#pragma unroll
    for (int ks=0; ks<2; ++ks) {
      const int off = (((ks*4 + (lane>>4)) ^ (lane & 7)) * 8);
      f16x8 af[4], bf[4];
#pragma unroll
      for (int fm=0; fm<4; ++fm)
        af[fm] = *(const f16x8*)&As[(wm*64 + fm*16 + (lane&15))*64 + off];
#pragma unroll
      for (int fn=0; fn<4; ++fn)
        bf[fn] = *(const f16x8*)&Bs[(wn*64 + fn*16 + (lane&15))*64 + off];
#pragma unroll
      for (int fm=0; fm<4; ++fm)
#pragma unroll
        for (int fn=0; fn<4; ++fn)
          acc[fm][fn] = __builtin_amdgcn_mfma_f32_16x16x32_f16(af[fm], bf[fn], acc[fm][fn], 0,0,0);
    }
    __syncthreads();
  }

  const int row0 = mbase + wm*64 + (lane>>4)*4;
  const int col0 = nbase + wn*64 + (lane&15);
#pragma unroll
  for (int fm=0; fm<4; ++fm)
#pragma unroll
    for (int fn=0; fn<4; ++fn)
#pragma unroll
      for (int r=0;r<4;r++)
        C[(size_t)(row0 + fm*16 + r)*ldc + (col0 + fn*16)] = (f16)acc[fm][fn][r];
}

// all 4 weight-fold GEMMs in one dispatch (86 blocks)
__global__ __launch_bounds__(256) void fold_all(
    const f16* __restrict__ BtA,  const f16* __restrict__ uW2h,
    const f16* __restrict__ mW2h, const f16* __restrict__ uW1aT,
    const f16* __restrict__ uW1bT,const f16* __restrict__ oWTh,
    f16* __restrict__ BtPQ, f16* __restrict__ BtU, f16* __restrict__ Wp2t)
{
  __shared__ f16 As[128*64];
  __shared__ f16 Bs[128*64];
  const int b = blockIdx.x;
  if (b < 40) {                 // BtPQ[l] = BtA[l] @ uW2h[l-1]^T, l=z+1 (z 0..4)
    int z = b >> 3, rem = b & 7, x = rem & 3, y = rem >> 2;
    gemm_core256(BtA + (size_t)(z+1)*131072, 256, uW2h + (size_t)z*65536, 256,
                 BtPQ + (size_t)(z+1)*131072, 256, x*128, y*128, As, Bs);
  } else if (b < 60) {          // BtU[l] 1st half = uW1aT[l] @ uW2h[l-1]^T
    int rem = b - 40, z = rem >> 2, r2 = rem & 3, x = r2 & 1, y = r2 >> 1;
    gemm_core256(uW1aT + (size_t)(z+1)*65536, 256, uW2h + (size_t)z*65536, 256,
                 BtU + (size_t)(z+1)*131072, 512, x*128, y*128, As, Bs);
  } else if (b < 84) {          // BtU[l] 2nd half = uW1bT[l] @ mW2h[l]^T, l=z 0..5
    int rem = b - 60, z = rem >> 2, r2 = rem & 3, x = r2 & 1, y = r2 >> 1;
    gemm_core256(uW1bT + (size_t)z*65536, 256, mW2h + (size_t)z*65536, 256,
                 BtU + (size_t)z*131072 + 256, 512, x*128, y*128, As, Bs);
  } else {                      // Wp2t = oWTh @ uW2h[5]^T
    int y = b - 84;
    gemm_core256(oWTh, 256, uW2h + (size_t)5*65536, 256,
                 Wp2t, 256, 0, y*128, As, Bs);
  }
}

// R[n] = sum over valid dirs of relu(P[src]+Q[n]+cvec_d+(si/256)*wsi+(sj/256)*wsj)
// R1=0: PQ [N,512] cols 0..255 = P, 256..511 = Q.  R1=1: P/Q analytic from g.
template<int R1>
__global__ __launch_bounds__(256) void edge_fuse(
    const f16* __restrict__ PQ, f16* __restrict__ UR,
    const float* __restrict__ cvec, const float* __restrict__ wsi_,
    const float* __restrict__ wsj_,
    const int* __restrict__ gridv, const float* __restrict__ pa,
    const float* __restrict__ pc)
{
  const int t  = threadIdx.x;
  const int ln = t >> 5, ch = t & 31;
  const int n  = blockIdx.x*8 + ln;
  const int i  = n >> 8, j = n & 255;
  const int co = ch*8;

  float q[8], pa0[8], pc0[8];
  if (R1) {
    float g = (float)gridv[n];
#pragma unroll
    for (int e=0;e<8;e++) {
      pa0[e] = pa[co+e]; pc0[e] = pc[co+e];
      q[e] = g*pa[256+co+e] + pc[256+co+e];
    }
  } else {
    f16x8 qv = *(const f16x8*)&PQ[(size_t)n*512 + 256 + co];
#pragma unroll
    for (int e=0;e<8;e++) q[e] = (float)qv[e];
  }
  float wi[8], wj[8];
#pragma unroll
  for (int e=0;e<8;e++){ wi[e]=wsi_[co+e]; wj[e]=wsj_[co+e]; }
  float acc[8];
#pragma unroll
  for (int e=0;e<8;e++) acc[e]=0.f;

  const int DI[4] = {-1,1,0,0};
  const int DJ[4] = {0,0,-1,1};
#pragma unroll
  for (int d=0; d<4; ++d) {
    int si = i - DI[d], sj = j - DJ[d];
    if (si>=0 && si<HG && sj>=0 && sj<WGD) {
      int s = si*WGD + sj;
      float fsi = si * (1.f/HG), fsj = sj * (1.f/WGD);
      float pvf[8];
      if (R1) {
        float gs = (float)gridv[s];
#pragma unroll
        for (int e=0;e<8;e++) pvf[e] = gs*pa0[e] + pc0[e];
      } else {
        f16x8 pv = *(const f16x8*)&PQ[(size_t)s*512 + co];
#pragma unroll
        for (int e=0;e<8;e++) pvf[e] = (float)pv[e];
      }
#pragma unroll
      for (int e=0;e<8;e++) {
        float v = pvf[e] + q[e] + cvec[d*256+co+e] + fsi*wi[e] + fsj*wj[e];
        acc[e] += fmaxf(v, 0.f);
      }
    }
  }
  f16x8 outv;
#pragma unroll
  for (int e=0;e<8;e++) outv[e] = (f16)acc[e];
  *(f16x8*)&UR[(size_t)n*512 + 256 + co] = outv;
}

// out[n,0..9] = U6[n,:] @ Wp2t^T + ob2  via MFMA, 1 wave = 16 nodes
__global__ __launch_bounds__(256) void out_mfma(
    const f16* __restrict__ U,        // lda 512
    const f16* __restrict__ Wp2t,     // [128][256], rows >=10 zero
    const float* __restrict__ ob2,
    float* __restrict__ out)
{
  int lane = threadIdx.x & 63;
  int wv   = threadIdx.x >> 6;
  int nbase = blockIdx.x*64 + wv*16;
  f32x4 acc = (f32x4){0.f,0.f,0.f,0.f};
  int r  = lane & 15;
  int kg = (lane >> 4) * 8;
  const f16* Up = U + (size_t)(nbase + r)*512 + kg;
  const f16* Bp = Wp2t + r*256 + kg;
#pragma unroll
  for (int kt=0; kt<8; ++kt) {
    f16x8 af = *(const f16x8*)(Up + kt*32);
    f16x8 bf = *(const f16x8*)(Bp + kt*32);
    acc = __builtin_amdgcn_mfma_f32_16x16x32_f16(af, bf, acc, 0,0,0);
  }
  int col = lane & 15;
  int row0 = (lane>>4)*4;
  if (col < 10) {
    float bo = ob2[col];
#pragma unroll
    for (int rr=0; rr<4; ++rr)
      out[(size_t)(nbase + row0 + rr)*10 + col] = acc[rr] + bo;
  }
}

// ---- prep: all 4 transpose-casts in ONE dispatch (z = q*6 + l) ----
__global__ __launch_bounds__(256) void tcast_all(
    const float* __restrict__ mW1, const float* __restrict__ uW1,
    f16* __restrict__ BtA, f16* __restrict__ uW1aT, f16* __restrict__ uW1bT)
{
  __shared__ float tbuf[32][33];
  const int z = blockIdx.z;
  const int q = z / 6, l = z % 6;
  const float* s;
  f16* d;
  if (q == 0)      { s = mW1 + (size_t)l*516*256;          d = BtA   + (size_t)l*131072; }
  else if (q == 1) { s = mW1 + (size_t)l*516*256 + 65536;  d = BtA   + (size_t)l*131072 + 65536; }
  else if (q == 2) { s = uW1 + (size_t)l*131072;           d = uW1aT + (size_t)l*65536; }
  else             { s = uW1 + (size_t)l*131072 + 65536;   d = uW1bT + (size_t)l*65536; }
  const int bc = blockIdx.x*32;
  const int br = blockIdx.y*32;
  const int tx = threadIdx.x & 31, ty = threadIdx.x >> 5;
#pragma unroll
  for (int rr=0; rr<4; ++rr)
    tbuf[ty+rr*8][tx] = s[(size_t)(br+ty+rr*8)*256 + bc+tx];
  __syncthreads();
#pragma unroll
  for (int rr=0; rr<4; ++rr)
    d[(size_t)(bc+ty+rr*8)*256 + br+tx] = (f16)tbuf[tx][ty+rr*8];
}

// ---- prep: everything small in ONE dispatch ----
// [0,1536): uW2h/mW2h casts | [1536,1664): oWTh | [1664,1670): cvec/wsi/wsj
// [1670,1694): vecB reduces | [1694,1742): pqb reduces | 1742: ob2
__global__ __launch_bounds__(256) void prep_small(
    const float* __restrict__ uW2, const float* __restrict__ mW2,
    const float* __restrict__ oW,  const float* __restrict__ mW1,
    const float* __restrict__ mb1, const float* __restrict__ mb2,
    const float* __restrict__ uW1, const float* __restrict__ ub1,
    const float* __restrict__ ub2, const float* __restrict__ nb,
    const float* __restrict__ nW,  const float* __restrict__ ob,
    f16* __restrict__ uW2h, f16* __restrict__ mW2h, f16* __restrict__ oWTh,
    float* __restrict__ cvec, float* __restrict__ wsi_, float* __restrict__ wsj_,
    float* __restrict__ v2, float* __restrict__ ubias, float* __restrict__ avec,
    float* __restrict__ pqb, float* __restrict__ pa, float* __restrict__ pc,
    float* __restrict__ ob2)
{
  __shared__ float red[3][4][64];
  const int b = blockIdx.x;
  const int tid = threadIdx.x;
  if (b < 1536) {
    int idx = b*256 + tid;
    uW2h[idx] = (f16)uW2[idx];
    mW2h[idx] = (f16)mW2[idx];
  } else if (b < 1664) {
    int c = b - 1536, j = tid;
    oWTh[c*256 + j] = (c < 10) ? (f16)oW[j*10 + c] : (f16)0.f;
  } else if (b < 1670) {
    int l = b - 1664, j = tid;
    const float* base = mW1 + (size_t)l*516*256;
    float w512 = base[512*256 + j], w513 = base[513*256 + j];
    float b1 = mb1[l*256 + j];
    const int DI[4] = {-1,1,0,0};
    const int DJ[4] = {0,0,-1,1};
    for (int d=0;d<4;d++)
      cvec[(l*4+d)*256 + j] = (float)DI[d]*w512 + (float)DJ[d]*w513 + b1;
    wsi_[l*256+j] = base[514*256 + j];
    wsj_[l*256+j] = base[515*256 + j];
  } else if (b < 1694) {
    int pr = tid & 63, q = tid >> 6;
    int pair = (b-1670)*64 + pr;
    int l = pair >> 8, j = pair & 255;
    const float* prevb = l ? (ub2 + (l-1)*256) : nb;
    float s1=0.f, s2=0.f, s3=0.f;
    for (int t = q*64; t < q*64+64; ++t) {
      s1 += mb2[l*256+t] * uW1[((size_t)l*512+256+t)*256 + j];
      s2 += prevb[t]     * uW1[((size_t)l*512+t)*256 + j];
      if (l==0) s3 += nW[t] * uW1[(size_t)t*256 + j];
    }
    red[0][q][pr]=s1; red[1][q][pr]=s2; red[2][q][pr]=s3;
    __syncthreads();
    if (q==0) {
      float a = red[0][0][pr]+red[0][1][pr]+red[0][2][pr]+red[0][3][pr];
      float bb = red[1][0][pr]+red[1][1][pr]+red[1][2][pr]+red[1][3][pr];
      v2[pair] = a;
      ubias[pair] = ub1[pair] + bb;
      if (l==0) avec[j] = red[2][0][pr]+red[2][1][pr]+red[2][2][pr]+red[2][3][pr];
    }
  } else if (b < 1742) {
    int pr = tid & 63, q = tid >> 6;
    int pair = (b-1694)*64 + pr;
    int l = pair >> 9, c = pair & 511;
    int rowoff = (c < 256) ? 0 : 256;
    int cc = c & 255;
    const float* base = mW1 + (size_t)l*516*256 + (size_t)rowoff*256 + cc;
    float s1=0.f, s2=0.f;
    if (l==0) {
      for (int j=q*64; j<q*64+64; ++j) { float wv = base[(size_t)j*256]; s1 += nW[j]*wv; s2 += nb[j]*wv; }
    } else {
      const float* pb = ub2 + (l-1)*256;
      for (int j=q*64; j<q*64+64; ++j) s1 += pb[j]*base[(size_t)j*256];
    }
    red[0][q][pr]=s1; red[1][q][pr]=s2;
    __syncthreads();
    if (q==0) {
      float a = red[0][0][pr]+red[0][1][pr]+red[0][2][pr]+red[0][3][pr];
      if (l==0) { pa[c]=a; pc[c]=red[1][0][pr]+red[1][1][pr]+red[1][2][pr]+red[1][3][pr]; }
      else pqb[pair] = a;
    }
  } else {
    int c = tid >> 4, jg = tid & 15;
    float s = 0.f;
    if (c < 10)
      for (int j=jg*16; j<jg*16+16; ++j) s += ub2[5*256+j]*oW[j*10+c];
    red[0][c>>2][(c&3)*16+jg] = s;
    __syncthreads();
    if (jg==0 && c < 16) {
      float a=0.f;
      for (int t2=0;t2<16;t2++) a += red[0][c>>2][(c&3)*16+t2];
      ob2[c] = (c < 10) ? a + ob[c] : 0.f;
    }
  }
}

extern "C" void kernel_launch(void* const* d_in, const int* in_sizes, int n_in,
                              void* d_out, int out_size, void* d_ws, size_t ws_size,
                              hipStream_t stream)
{
  const int*   gridv = (const int*) d_in[0];
  const float* nW   = (const float*)d_in[3];
  const float* nb   = (const float*)d_in[4];
  const float* mW1  = (const float*)d_in[5];
  const float* mb1  = (const float*)d_in[6];
  const float* mW2  = (const float*)d_in[7];
  const float* mb2  = (const float*)d_in[8];
  const float* uW1  = (const float*)d_in[9];
  const float* ub1  = (const float*)d_in[10];
  const float* uW2  = (const float*)d_in[11];
  const float* ub2  = (const float*)d_in[12];
  const float* oW   = (const float*)d_in[13];
  const float* ob   = (const float*)d_in[14];
  float* out = (float*)d_out;

  char* ws = (char*)d_ws;
  size_t off = 0;
  f16* URa  = (f16*)(ws + off); off += (size_t)NN*512*2;
  f16* URb  = (f16*)(ws + off); off += (size_t)NN*512*2;
  f16* BtA  = (f16*)(ws + off); off += 6*512*256*2;
  f16* BtPQ = (f16*)(ws + off); off += 6*512*256*2;   // slot 0 unused
  f16* BtU  = (f16*)(ws + off); off += 6*256*512*2;
  f16* uW2h = (f16*)(ws + off); off += 6*256*256*2;
  f16* mW2h = (f16*)(ws + off); off += 6*256*256*2;
  f16* uW1aT= (f16*)(ws + off); off += 6*256*256*2;
  f16* uW1bT= (f16*)(ws + off); off += 6*256*256*2;
  f16* oWTh = (f16*)(ws + off); off += 128*256*2;
  f16* Wp2t = (f16*)(ws + off); off += 128*256*2;
  float* cvec = (float*)(ws + off); off += 6*4*256*4;
  float* wsi_ = (float*)(ws + off); off += 6*256*4;
  float* wsj_ = (float*)(ws + off); off += 6*256*4;
  float* v2   = (float*)(ws + off); off += 6*256*4;
  float* ubias= (float*)(ws + off); off += 6*256*4;
  float* pqb  = (float*)(ws + off); off += 6*512*4;   // slot 0 unused
  float* pa   = (float*)(ws + off); off += 512*4;
  float* pc   = (float*)(ws + off); off += 512*4;
  float* avec = (float*)(ws + off); off += 256*4;
  float* ob2  = (float*)(ws + off); off += 16*4;

  // ---- prep (3 dispatches total) ----
  tcast_all<<<dim3(8,8,24),256,0,stream>>>(mW1, uW1, BtA, uW1aT, uW1bT);
  prep_small<<<1743,256,0,stream>>>(uW2, mW2, oW, mW1, mb1, mb2, uW1, ub1, ub2,
                                    nb, nW, ob,
                                    uW2h, mW2h, oWTh, cvec, wsi_, wsj_,
                                    v2, ubias, avec, pqb, pa, pc, ob2);
  fold_all<<<86,256,0,stream>>>(BtA, uW2h, mW2h, uW1aT, uW1bT, oWTh,
                                BtPQ, BtU, Wp2t);

  // ---- layer 1 (rank-1 input, P/Q analytic) ----
  edge_fuse<1><<<8192,256,0,stream>>>(nullptr, URa, cvec, wsi_, wsj_, gridv, pa, pc);
  gemm8<256,3><<<dim3(512,1),512,0,stream>>>(
      URa + 256, 512, BtU + 256, 512, URa, 512,
      ubias, v2, avec, gridv);

  // ---- layers 2..6 ----
  f16* cur = URa; f16* nxt = URb;
  for (int l=1;l<NL;l++){
    // PQ_l = U_{l-1} @ BtPQ[l]^T + pqb[l]
    gemm8<256,2><<<dim3(512,2),512,0,stream>>>(
        cur, 512, BtPQ + (size_t)l*131072, 256, nxt, 512,
        pqb + l*512, nullptr, nullptr, nullptr);
    // R_l -> cur cols 256..511
    edge_fuse<0><<<8192,256,0,stream>>>(nxt, cur, cvec + l*1024, wsi_ + l*256, wsj_ + l*256,
                                        nullptr, nullptr, nullptr);
    // U_l = relu([U|R] @ BtU[l]^T + ubias + deg*v2) -> nxt cols 0..255
    gemm8<512,1><<<dim3(512,1),512,0,stream>>>(
        cur, 512, BtU + (size_t)l*131072, 512, nxt, 512,
        ubias + l*256, v2 + l*256, nullptr, nullptr);
    f16* t = cur; cur = nxt; nxt = t;
  }

  // out = U6 @ Wp2t^T + ob2
  out_mfma<<<1024,256,0,stream>>>(cur, Wp2t, ob2, out);
}

// Round 8
// 522.504 us; speedup vs baseline: 1.2655x; 1.0205x over previous
//
#include <hip/hip_runtime.h>

#define HG 256
#define WGD 256
#define NN (HG*WGD)
#define NL 6

typedef _Float16 f16;
typedef _Float16 f16x8 __attribute__((ext_vector_type(8)));
typedef float f32x4 __attribute__((ext_vector_type(4)));

__device__ __forceinline__ void gload_lds16(const f16* g, f16* lds) {
  __builtin_amdgcn_global_load_lds(
      (const __attribute__((address_space(1))) unsigned int*)g,
      (__attribute__((address_space(3))) unsigned int*)lds, 16, 0, 0);
}

// ---- 8-wave 128x256 GEMM, double-buffered LDS, 2-phase pipeline ----
// C[M,N] = A[M,KK] @ Bt[N,KK]^T, f16 in, f32 accum, f16 out. N = gridDim.y*256.
// bid is bx-MAJOR before XCD-chunk swizzle: the gridDim.y N-tiles sharing an
// A-panel are adjacent in swizzled space -> same XCD -> A re-read is L2-hit.
// LDS XOR-swizzled (T2); staged via pre-swizzled global source.
// EPI: 1 +bias+deg*v2, relu | 2 +bias | 3 EPI1 + g*avec (layer-1)
template<int KK, int EPI>
__global__ __launch_bounds__(512) void gemm8(
    const f16* __restrict__ A, int lda,
    const f16* __restrict__ Bt, int ldb,
    f16* __restrict__ C, int ldc,
    const float* __restrict__ bias,
    const float* __restrict__ v2,
    const float* __restrict__ avec,
    const int* __restrict__ gridv)
{
  constexpr int NT = KK/64;
  __shared__ f16 As[2][128*64];   // 32 KB
  __shared__ f16 Bs[2][256*64];   // 64 KB
  const int tid  = threadIdx.x;
  const int lane = tid & 63;
  const int w    = tid >> 6;          // 0..7
  const int wm   = w >> 2, wn = w & 3;

  // bx-major linearization + bijective XCD chunk swizzle (nwg % 8 == 0)
  int bid = blockIdx.x * gridDim.y + blockIdx.y;
  const int nwg = gridDim.x * gridDim.y;
  { int q = nwg >> 3; bid = (bid & 7) * q + (bid >> 3); }
  const int by = bid % gridDim.y, bx = bid / gridDim.y;
  const int mbase = bx * 128;
  const int nbase = by * 256;

  f32x4 acc[4][4];
#pragma unroll
  for (int a=0;a<4;a++)
#pragma unroll
    for (int b=0;b<4;b++) acc[a][b] = (f32x4){0.f,0.f,0.f,0.f};

  const int r8  = lane >> 3;                 // 0..7
  const int c8s = ((lane & 7) ^ r8) * 8;     // pre-swizzled src col (f16)

#define STAGE8(kt, buf)                                                        \
  {                                                                            \
    const f16* Ab = A + (size_t)mbase*lda + (kt)*64;                           \
    _Pragma("unroll")                                                          \
    for (int p=0;p<2;p++) {                                                    \
      int qc = p*8 + w;                                                        \
      gload_lds16(Ab + (size_t)(qc*8 + r8)*lda + c8s, &As[buf][qc*512]);       \
    }                                                                          \
    const f16* Bb = Bt + (size_t)nbase*ldb + (kt)*64;                          \
    _Pragma("unroll")                                                          \
    for (int p=0;p<4;p++) {                                                    \
      int qc = p*8 + w;                                                        \
      gload_lds16(Bb + (size_t)(qc*8 + r8)*ldb + c8s, &Bs[buf][qc*512]);       \
    }                                                                          \
  }

  STAGE8(0, 0);
  __syncthreads();
  int cur = 0;
  for (int kt = 0; kt < NT; ++kt) {
    if (kt + 1 < NT) STAGE8(kt + 1, cur ^ 1);
    const f16* Acur = &As[cur][0];
    const f16* Bcur = &Bs[cur][0];
#pragma unroll
    for (int ks=0; ks<2; ++ks) {
      const int off = (((ks*4 + (lane>>4)) ^ (lane & 7)) * 8);
      f16x8 af[4], bf[4];
#pragma unroll
      for (int fm=0; fm<4; ++fm)
        af[fm] = *(const f16x8*)&Acur[(wm*64 + fm*16 + (lane&15))*64 + off];
#pragma unroll
      for (int fn=0; fn<4; ++fn)
        bf[fn] = *(const f16x8*)&Bcur[(wn*64 + fn*16 + (lane&15))*64 + off];
#pragma unroll
      for (int fm=0; fm<4; ++fm)
#pragma unroll
        for (int fn=0; fn<4; ++fn)
          acc[fm][fn] = __builtin_amdgcn_mfma_f32_16x16x32_f16(af[fm], bf[fn], acc[fm][fn], 0,0,0);
    }
    __syncthreads();
    cur ^= 1;
  }
#undef STAGE8

  const int row0 = mbase + wm*64 + (lane>>4)*4;
  const int col0 = nbase + wn*64 + (lane&15);
#pragma unroll
  for (int fm=0; fm<4; ++fm) {
#pragma unroll
    for (int fn=0; fn<4; ++fn) {
      const int col = col0 + fn*16;
#pragma unroll
      for (int r=0;r<4;r++) {
        int row = row0 + fm*16 + r;
        float v = acc[fm][fn][r];
        if (EPI==1 || EPI==3) {
          int i = row >> 8, j = row & 255;
          float deg = (float)((i>0)+(i<255)+(j>0)+(j<255));
          v += bias[col & 255] + deg * v2[col & 255];
          if (EPI==3) v += (float)gridv[row] * avec[col & 255];
          v = fmaxf(v, 0.f);
        } else if (EPI==2) {
          v += bias[col];
        }
        C[(size_t)row*ldc + col] = (f16)v;
      }
    }
  }
}

// ---- 4-wave 128x128 GEMM core (K=256), used by the merged fold dispatch ----
__device__ __forceinline__ void gemm_core256(
    const f16* __restrict__ A, int lda,
    const f16* __restrict__ Bt, int ldb,
    f16* __restrict__ C, int ldc,
    int mbase, int nbase, f16* As, f16* Bs)
{
  const int tid  = threadIdx.x;
  const int lane = tid & 63;
  const int w    = tid >> 6;
  const int wm   = w >> 1, wn = w & 1;

  f32x4 acc[4][4];
#pragma unroll
  for (int a=0;a<4;a++)
#pragma unroll
    for (int b=0;b<4;b++) acc[a][b] = (f32x4){0.f,0.f,0.f,0.f};

  const int r8  = lane >> 3;
  const int c8s = ((lane & 7) ^ r8) * 8;

  for (int kt = 0; kt < 4; ++kt) {
    const f16* Ab = A  + (size_t)(mbase + w*32)*lda + kt*64;
    const f16* Bb = Bt + (size_t)(nbase + w*32)*ldb + kt*64;
#pragma unroll
    for (int i=0;i<4;i++) {
      gload_lds16(Ab + (size_t)(i*8 + r8)*lda + c8s, &As[(w*32+i*8)*64]);
      gload_lds16(Bb + (size_t)(i*8 + r8)*ldb + c8s, &Bs[(w*32+i*8)*64]);
    }
    __syncthreads();
#pragma unroll
    for (int ks=0; ks<2; ++ks) {
      const int off = (((ks*4 + (lane>>4)) ^ (lane & 7)) * 8);
      f16x8 af[4], bf[4];
#pragma unroll
      for (int fm=0; fm<4; ++fm)
        af[fm] = *(const f16x8*)&As[(wm*64 + fm*16 + (lane&15))*64 + off];
#pragma unroll
      for (int fn=0; fn<4; ++fn)
        bf[fn] = *(const f16x8*)&Bs[(wn*64 + fn*16 + (lane&15))*64 + off];
#pragma unroll
      for (int fm=0; fm<4; ++fm)
#pragma unroll
        for (int fn=0; fn<4; ++fn)
          acc[fm][fn] = __builtin_amdgcn_mfma_f32_16x16x32_f16(af[fm], bf[fn], acc[fm][fn], 0,0,0);
    }
    __syncthreads();
  }

  const int row0 = mbase + wm*64 + (lane>>4)*4;
  const int col0 = nbase + wn*64 + (lane&15);
#pragma unroll
  for (int fm=0; fm<4; ++fm)
#pragma unroll
    for (int fn=0; fn<4; ++fn)
#pragma unroll
      for (int r=0;r<4;r++)
        C[(size_t)(row0 + fm*16 + r)*ldc + (col0 + fn*16)] = (f16)acc[fm][fn][r];
}

// all 4 weight-fold GEMMs in one dispatch (86 blocks)
__global__ __launch_bounds__(256) void fold_all(
    const f16* __restrict__ BtA,  const f16* __restrict__ uW2h,
    const f16* __restrict__ mW2h, const f16* __restrict__ uW1aT,
    const f16* __restrict__ uW1bT,const f16* __restrict__ oWTh,
    f16* __restrict__ BtPQ, f16* __restrict__ BtU, f16* __restrict__ Wp2t)
{
  __shared__ f16 As[128*64];
  __shared__ f16 Bs[128*64];
  const int b = blockIdx.x;
  if (b < 40) {                 // BtPQ[l] = BtA[l] @ uW2h[l-1]^T, l=z+1
    int z = b >> 3, rem = b & 7, x = rem & 3, y = rem >> 2;
    gemm_core256(BtA + (size_t)(z+1)*131072, 256, uW2h + (size_t)z*65536, 256,
                 BtPQ + (size_t)(z+1)*131072, 256, x*128, y*128, As, Bs);
  } else if (b < 60) {          // BtU[l] 1st half = uW1aT[l] @ uW2h[l-1]^T
    int rem = b - 40, z = rem >> 2, r2 = rem & 3, x = r2 & 1, y = r2 >> 1;
    gemm_core256(uW1aT + (size_t)(z+1)*65536, 256, uW2h + (size_t)z*65536, 256,
                 BtU + (size_t)(z+1)*131072, 512, x*128, y*128, As, Bs);
  } else if (b < 84) {          // BtU[l] 2nd half = uW1bT[l] @ mW2h[l]^T
    int rem = b - 60, z = rem >> 2, r2 = rem & 3, x = r2 & 1, y = r2 >> 1;
    gemm_core256(uW1bT + (size_t)z*65536, 256, mW2h + (size_t)z*65536, 256,
                 BtU + (size_t)z*131072 + 256, 512, x*128, y*128, As, Bs);
  } else {                      // Wp2t = oWTh @ uW2h[5]^T
    int y = b - 84;
    gemm_core256(oWTh, 256, uW2h + (size_t)5*65536, 256,
                 Wp2t, 256, 0, y*128, As, Bs);
  }
}

// R[n] = sum over valid dirs of relu(P[src]+Q[n]+cvec_d+(si/256)*wsi+(sj/256)*wsj)
// XCD band swizzle: each XCD owns a contiguous 8192-node band -> vertical
// neighbor P-rows stay in the same L2; band matches gemm8's chunk mapping.
// R1=0: PQ [N,512] cols 0..255 = P, 256..511 = Q.  R1=1: P/Q analytic from g.
template<int R1>
__global__ __launch_bounds__(256) void edge_fuse(
    const f16* __restrict__ PQ, f16* __restrict__ UR,
    const float* __restrict__ cvec, const float* __restrict__ wsi_,
    const float* __restrict__ wsj_,
    const int* __restrict__ gridv, const float* __restrict__ pa,
    const float* __restrict__ pc)
{
  const int t  = threadIdx.x;
  const int ln = t >> 5, ch = t & 31;
  int bid = blockIdx.x;                      // 8192 blocks
  bid = (bid & 7) * 1024 + (bid >> 3);       // bijective band swizzle
  const int n  = bid*8 + ln;
  const int i  = n >> 8, j = n & 255;
  const int co = ch*8;

  float q[8], pa0[8], pc0[8];
  if (R1) {
    float g = (float)gridv[n];
#pragma unroll
    for (int e=0;e<8;e++) {
      pa0[e] = pa[co+e]; pc0[e] = pc[co+e];
      q[e] = g*pa[256+co+e] + pc[256+co+e];
    }
  } else {
    f16x8 qv = *(const f16x8*)&PQ[(size_t)n*512 + 256 + co];
#pragma unroll
    for (int e=0;e<8;e++) q[e] = (float)qv[e];
  }
  float wi[8], wj[8];
#pragma unroll
  for (int e=0;e<8;e++){ wi[e]=wsi_[co+e]; wj[e]=wsj_[co+e]; }
  float acc[8];
#pragma unroll
  for (int e=0;e<8;e++) acc[e]=0.f;

  const int DI[4] = {-1,1,0,0};
  const int DJ[4] = {0,0,-1,1};
#pragma unroll
  for (int d=0; d<4; ++d) {
    int si = i - DI[d], sj = j - DJ[d];
    if (si>=0 && si<HG && sj>=0 && sj<WGD) {
      int s = si*WGD + sj;
      float fsi = si * (1.f/HG), fsj = sj * (1.f/WGD);
      float pvf[8];
      if (R1) {
        float gs = (float)gridv[s];
#pragma unroll
        for (int e=0;e<8;e++) pvf[e] = gs*pa0[e] + pc0[e];
      } else {
        f16x8 pv = *(const f16x8*)&PQ[(size_t)s*512 + co];
#pragma unroll
        for (int e=0;e<8;e++) pvf[e] = (float)pv[e];
      }
#pragma unroll
      for (int e=0;e<8;e++) {
        float v = pvf[e] + q[e] + cvec[d*256+co+e] + fsi*wi[e] + fsj*wj[e];
        acc[e] += fmaxf(v, 0.f);
      }
    }
  }
  f16x8 outv;
#pragma unroll
  for (int e=0;e<8;e++) outv[e] = (f16)acc[e];
  *(f16x8*)&UR[(size_t)n*512 + 256 + co] = outv;
}

// out[n,0..9] = U6[n,:] @ Wp2t^T + ob2  via MFMA, 1 wave = 16 nodes
__global__ __launch_bounds__(256) void out_mfma(
    const f16* __restrict__ U,        // lda 512
    const f16* __restrict__ Wp2t,     // [128][256], rows >=10 zero
    const float* __restrict__ ob2,
    float* __restrict__ out)
{
  int lane = threadIdx.x & 63;
  int wv   = threadIdx.x >> 6;
  int nbase = blockIdx.x*64 + wv*16;
  f32x4 acc = (f32x4){0.f,0.f,0.f,0.f};
  int r  = lane & 15;
  int kg = (lane >> 4) * 8;
  const f16* Up = U + (size_t)(nbase + r)*512 + kg;
  const f16* Bp = Wp2t + r*256 + kg;
#pragma unroll
  for (int kt=0; kt<8; ++kt) {
    f16x8 af = *(const f16x8*)(Up + kt*32);
    f16x8 bf = *(const f16x8*)(Bp + kt*32);
    acc = __builtin_amdgcn_mfma_f32_16x16x32_f16(af, bf, acc, 0,0,0);
  }
  int col = lane & 15;
  int row0 = (lane>>4)*4;
  if (col < 10) {
    float bo = ob2[col];
#pragma unroll
    for (int rr=0; rr<4; ++rr)
      out[(size_t)(nbase + row0 + rr)*10 + col] = acc[rr] + bo;
  }
}

// ---- prep: everything small + all transpose-casts in ONE dispatch ----
// [0,1536): uW2h/mW2h casts | [1536,1664): oWTh | [1664,1670): cvec/wsi/wsj
// [1670,1694): vecB reduces | [1694,1742): pqb reduces | 1742: ob2
// [1743,3279): tcast tiles (t = b-1743; z=t/64; rem=t%64; bx=rem&7, by=rem>>3)
__global__ __launch_bounds__(256) void prep_small(
    const float* __restrict__ uW2, const float* __restrict__ mW2,
    const float* __restrict__ oW,  const float* __restrict__ mW1,
    const float* __restrict__ mb1, const float* __restrict__ mb2,
    const float* __restrict__ uW1, const float* __restrict__ ub1,
    const float* __restrict__ ub2, const float* __restrict__ nb,
    const float* __restrict__ nW,  const float* __restrict__ ob,
    f16* __restrict__ uW2h, f16* __restrict__ mW2h, f16* __restrict__ oWTh,
    float* __restrict__ cvec, float* __restrict__ wsi_, float* __restrict__ wsj_,
    float* __restrict__ v2, float* __restrict__ ubias, float* __restrict__ avec,
    float* __restrict__ pqb, float* __restrict__ pa, float* __restrict__ pc,
    float* __restrict__ ob2,
    f16* __restrict__ BtA, f16* __restrict__ uW1aT, f16* __restrict__ uW1bT)
{
  __shared__ float red[3][4][64];
  __shared__ float tbuf[32][33];
  const int b = blockIdx.x;
  const int tid = threadIdx.x;
  if (b < 1536) {
    int idx = b*256 + tid;
    uW2h[idx] = (f16)uW2[idx];
    mW2h[idx] = (f16)mW2[idx];
  } else if (b < 1664) {
    int c = b - 1536, j = tid;
    oWTh[c*256 + j] = (c < 10) ? (f16)oW[j*10 + c] : (f16)0.f;
  } else if (b < 1670) {
    int l = b - 1664, j = tid;
    const float* base = mW1 + (size_t)l*516*256;
    float w512 = base[512*256 + j], w513 = base[513*256 + j];
    float b1 = mb1[l*256 + j];
    const int DI[4] = {-1,1,0,0};
    const int DJ[4] = {0,0,-1,1};
    for (int d=0;d<4;d++)
      cvec[(l*4+d)*256 + j] = (float)DI[d]*w512 + (float)DJ[d]*w513 + b1;
    wsi_[l*256+j] = base[514*256 + j];
    wsj_[l*256+j] = base[515*256 + j];
  } else if (b < 1694) {
    int pr = tid & 63, q = tid >> 6;
    int pair = (b-1670)*64 + pr;
    int l = pair >> 8, j = pair & 255;
    const float* prevb = l ? (ub2 + (l-1)*256) : nb;
    float s1=0.f, s2=0.f, s3=0.f;
    for (int t = q*64; t < q*64+64; ++t) {
      s1 += mb2[l*256+t] * uW1[((size_t)l*512+256+t)*256 + j];
      s2 += prevb[t]     * uW1[((size_t)l*512+t)*256 + j];
      if (l==0) s3 += nW[t] * uW1[(size_t)t*256 + j];
    }
    red[0][q][pr]=s1; red[1][q][pr]=s2; red[2][q][pr]=s3;
    __syncthreads();
    if (q==0) {
      float a = red[0][0][pr]+red[0][1][pr]+red[0][2][pr]+red[0][3][pr];
      float bb = red[1][0][pr]+red[1][1][pr]+red[1][2][pr]+red[1][3][pr];
      v2[pair] = a;
      ubias[pair] = ub1[pair] + bb;
      if (l==0) avec[j] = red[2][0][pr]+red[2][1][pr]+red[2][2][pr]+red[2][3][pr];
    }
  } else if (b < 1742) {
    int pr = tid & 63, q = tid >> 6;
    int pair = (b-1694)*64 + pr;
    int l = pair >> 9, c = pair & 511;
    int rowoff = (c < 256) ? 0 : 256;
    int cc = c & 255;
    const float* base = mW1 + (size_t)l*516*256 + (size_t)rowoff*256 + cc;
    float s1=0.f, s2=0.f;
    if (l==0) {
      for (int j=q*64; j<q*64+64; ++j) { float wv = base[(size_t)j*256]; s1 += nW[j]*wv; s2 += nb[j]*wv; }
    } else {
      const float* pb = ub2 + (l-1)*256;
      for (int j=q*64; j<q*64+64; ++j) s1 += pb[j]*base[(size_t)j*256];
    }
    red[0][q][pr]=s1; red[1][q][pr]=s2;
    __syncthreads();
    if (q==0) {
      float a = red[0][0][pr]+red[0][1][pr]+red[0][2][pr]+red[0][3][pr];
      if (l==0) { pa[c]=a; pc[c]=red[1][0][pr]+red[1][1][pr]+red[1][2][pr]+red[1][3][pr]; }
      else pqb[pair] = a;
    }
  } else if (b == 1742) {
    int c = tid >> 4, jg = tid & 15;
    float s = 0.f;
    if (c < 10)
      for (int j=jg*16; j<jg*16+16; ++j) s += ub2[5*256+j]*oW[j*10+c];
    red[0][c>>2][(c&3)*16+jg] = s;
    __syncthreads();
    if (jg==0 && c < 16) {
      float a=0.f;
      for (int t2=0;t2<16;t2++) a += red[0][c>>2][(c&3)*16+t2];
      ob2[c] = (c < 10) ? a + ob[c] : 0.f;
    }
  } else {
    // transpose-cast tiles
    int t = b - 1743;
    int z = t >> 6, rem = t & 63;
    int bxs = (rem & 7) * 32, bys = (rem >> 3) * 32;
    const int q = z / 6, l = z % 6;
    const float* s;
    f16* d;
    if (q == 0)      { s = mW1 + (size_t)l*516*256;          d = BtA   + (size_t)l*131072; }
    else if (q == 1) { s = mW1 + (size_t)l*516*256 + 65536;  d = BtA   + (size_t)l*131072 + 65536; }
    else if (q == 2) { s = uW1 + (size_t)l*131072;           d = uW1aT + (size_t)l*65536; }
    else             { s = uW1 + (size_t)l*131072 + 65536;   d = uW1bT + (size_t)l*65536; }
    const int tx = tid & 31, ty = tid >> 5;
#pragma unroll
    for (int rr=0; rr<4; ++rr)
      tbuf[ty+rr*8][tx] = s[(size_t)(bys+ty+rr*8)*256 + bxs+tx];
    __syncthreads();
#pragma unroll
    for (int rr=0; rr<4; ++rr)
      d[(size_t)(bxs+ty+rr*8)*256 + bys+tx] = (f16)tbuf[tx][ty+rr*8];
  }
}

extern "C" void kernel_launch(void* const* d_in, const int* in_sizes, int n_in,
                              void* d_out, int out_size, void* d_ws, size_t ws_size,
                              hipStream_t stream)
{
  const int*   gridv = (const int*) d_in[0];
  const float* nW   = (const float*)d_in[3];
  const float* nb   = (const float*)d_in[4];
  const float* mW1  = (const float*)d_in[5];
  const float* mb1  = (const float*)d_in[6];
  const float* mW2  = (const float*)d_in[7];
  const float* mb2  = (const float*)d_in[8];
  const float* uW1  = (const float*)d_in[9];
  const float* ub1  = (const float*)d_in[10];
  const float* uW2  = (const float*)d_in[11];
  const float* ub2  = (const float*)d_in[12];
  const float* oW   = (const float*)d_in[13];
  const float* ob   = (const float*)d_in[14];
  float* out = (float*)d_out;

  char* ws = (char*)d_ws;
  size_t off = 0;
  f16* URa  = (f16*)(ws + off); off += (size_t)NN*512*2;
  f16* URb  = (f16*)(ws + off); off += (size_t)NN*512*2;
  f16* BtA  = (f16*)(ws + off); off += 6*512*256*2;
  f16* BtPQ = (f16*)(ws + off); off += 6*512*256*2;   // slot 0 unused
  f16* BtU  = (f16*)(ws + off); off += 6*256*512*2;
  f16* uW2h = (f16*)(ws + off); off += 6*256*256*2;
  f16* mW2h = (f16*)(ws + off); off += 6*256*256*2;
  f16* uW1aT= (f16*)(ws + off); off += 6*256*256*2;
  f16* uW1bT= (f16*)(ws + off); off += 6*256*256*2;
  f16* oWTh = (f16*)(ws + off); off += 128*256*2;
  f16* Wp2t = (f16*)(ws + off); off += 128*256*2;
  float* cvec = (float*)(ws + off); off += 6*4*256*4;
  float* wsi_ = (float*)(ws + off); off += 6*256*4;
  float* wsj_ = (float*)(ws + off); off += 6*256*4;
  float* v2   = (float*)(ws + off); off += 6*256*4;
  float* ubias= (float*)(ws + off); off += 6*256*4;
  float* pqb  = (float*)(ws + off); off += 6*512*4;   // slot 0 unused
  float* pa   = (float*)(ws + off); off += 512*4;
  float* pc   = (float*)(ws + off); off += 512*4;
  float* avec = (float*)(ws + off); off += 256*4;
  float* ob2  = (float*)(ws + off); off += 16*4;

  // ---- prep (2 dispatches) ----
  prep_small<<<3279,256,0,stream>>>(uW2, mW2, oW, mW1, mb1, mb2, uW1, ub1, ub2,
                                    nb, nW, ob,
                                    uW2h, mW2h, oWTh, cvec, wsi_, wsj_,
                                    v2, ubias, avec, pqb, pa, pc, ob2,
                                    BtA, uW1aT, uW1bT);
  fold_all<<<86,256,0,stream>>>(BtA, uW2h, mW2h, uW1aT, uW1bT, oWTh,
                                BtPQ, BtU, Wp2t);

  // ---- layer 1 (rank-1 input, P/Q analytic) ----
  edge_fuse<1><<<8192,256,0,stream>>>(nullptr, URa, cvec, wsi_, wsj_, gridv, pa, pc);
  gemm8<256,3><<<dim3(512,1),512,0,stream>>>(
      URa + 256, 512, BtU + 256, 512, URa, 512,
      ubias, v2, avec, gridv);

  // ---- layers 2..6 ----
  f16* cur = URa; f16* nxt = URb;
  for (int l=1;l<NL;l++){
    // PQ_l = U_{l-1} @ BtPQ[l]^T + pqb[l]
    gemm8<256,2><<<dim3(512,2),512,0,stream>>>(
        cur, 512, BtPQ + (size_t)l*131072, 256, nxt, 512,
        pqb + l*512, nullptr, nullptr, nullptr);
    // R_l -> cur cols 256..511
    edge_fuse<0><<<8192,256,0,stream>>>(nxt, cur, cvec + l*1024, wsi_ + l*256, wsj_ + l*256,
                                        nullptr, nullptr, nullptr);
    // U_l = relu([U|R] @ BtU[l]^T + ubias + deg*v2) -> nxt cols 0..255
    gemm8<512,1><<<dim3(512,1),512,0,stream>>>(
        cur, 512, BtU + (size_t)l*131072, 512, nxt, 512,
        ubias + l*256, v2 + l*256, nullptr, nullptr);
    f16* t = cur; cur = nxt; nxt = t;
  }

  // out = U6 @ Wp2t^T + ob2
  out_mfma<<<1024,256,0,stream>>>(cur, Wp2t, ob2, out);
}

// Round 9
// 486.838 us; speedup vs baseline: 1.3582x; 1.0733x over previous
//
#include <hip/hip_runtime.h>

#define HG 256
#define WGD 256
#define NN (HG*WGD)
#define NL 6

typedef _Float16 f16;
typedef _Float16 f16x8 __attribute__((ext_vector_type(8)));
typedef float f32x4 __attribute__((ext_vector_type(4)));

__device__ __forceinline__ void gload_lds16(const f16* g, f16* lds) {
  __builtin_amdgcn_global_load_lds(
      (const __attribute__((address_space(1))) unsigned int*)g,
      (__attribute__((address_space(3))) unsigned int*)lds, 16, 0, 0);
}

// ---- 8-wave 128x256 GEMM, double-buffered LDS, 2-phase pipeline ----
// (used for layer-6 update only; merged kernel below handles layers 1..5)
template<int KK, int EPI>
__global__ __launch_bounds__(512) void gemm8(
    const f16* __restrict__ A, int lda,
    const f16* __restrict__ Bt, int ldb,
    f16* __restrict__ C, int ldc,
    const float* __restrict__ bias,
    const float* __restrict__ v2,
    const float* __restrict__ avec,
    const int* __restrict__ gridv)
{
  constexpr int NT = KK/64;
  __shared__ f16 As[2][128*64];
  __shared__ f16 Bs[2][256*64];
  const int tid  = threadIdx.x;
  const int lane = tid & 63;
  const int w    = tid >> 6;
  const int wm   = w >> 2, wn = w & 3;

  int bid = blockIdx.x * gridDim.y + blockIdx.y;
  const int nwg = gridDim.x * gridDim.y;
  { int q = nwg >> 3; bid = (bid & 7) * q + (bid >> 3); }
  const int by = bid % gridDim.y, bx = bid / gridDim.y;
  const int mbase = bx * 128;
  const int nbase = by * 256;

  f32x4 acc[4][4];
#pragma unroll
  for (int a=0;a<4;a++)
#pragma unroll
    for (int b=0;b<4;b++) acc[a][b] = (f32x4){0.f,0.f,0.f,0.f};

  const int r8  = lane >> 3;
  const int c8s = ((lane & 7) ^ r8) * 8;

#define STAGE8(kt, buf)                                                        \
  {                                                                            \
    const f16* Ab = A + (size_t)mbase*lda + (kt)*64;                           \
    _Pragma("unroll")                                                          \
    for (int p=0;p<2;p++) {                                                    \
      int qc = p*8 + w;                                                        \
      gload_lds16(Ab + (size_t)(qc*8 + r8)*lda + c8s, &As[buf][qc*512]);       \
    }                                                                          \
    const f16* Bb = Bt + (size_t)nbase*ldb + (kt)*64;                          \
    _Pragma("unroll")                                                          \
    for (int p=0;p<4;p++) {                                                    \
      int qc = p*8 + w;                                                        \
      gload_lds16(Bb + (size_t)(qc*8 + r8)*ldb + c8s, &Bs[buf][qc*512]);       \
    }                                                                          \
  }

  STAGE8(0, 0);
  __syncthreads();
  int cur = 0;
  for (int kt = 0; kt < NT; ++kt) {
    if (kt + 1 < NT) STAGE8(kt + 1, cur ^ 1);
    const f16* Acur = &As[cur][0];
    const f16* Bcur = &Bs[cur][0];
#pragma unroll
    for (int ks=0; ks<2; ++ks) {
      const int off = (((ks*4 + (lane>>4)) ^ (lane & 7)) * 8);
      f16x8 af[4], bf[4];
#pragma unroll
      for (int fm=0; fm<4; ++fm)
        af[fm] = *(const f16x8*)&Acur[(wm*64 + fm*16 + (lane&15))*64 + off];
#pragma unroll
      for (int fn=0; fn<4; ++fn)
        bf[fn] = *(const f16x8*)&Bcur[(wn*64 + fn*16 + (lane&15))*64 + off];
#pragma unroll
      for (int fm=0; fm<4; ++fm)
#pragma unroll
        for (int fn=0; fn<4; ++fn)
          acc[fm][fn] = __builtin_amdgcn_mfma_f32_16x16x32_f16(af[fm], bf[fn], acc[fm][fn], 0,0,0);
    }
    __syncthreads();
    cur ^= 1;
  }
#undef STAGE8

  const int row0 = mbase + wm*64 + (lane>>4)*4;
  const int col0 = nbase + wn*64 + (lane&15);
#pragma unroll
  for (int fm=0; fm<4; ++fm) {
#pragma unroll
    for (int fn=0; fn<4; ++fn) {
      const int col = col0 + fn*16;
#pragma unroll
      for (int r=0;r<4;r++) {
        int row = row0 + fm*16 + r;
        float v = acc[fm][fn][r];
        if (EPI==1 || EPI==3) {
          int i = row >> 8, j = row & 255;
          float deg = (float)((i>0)+(i<255)+(j>0)+(j<255));
          v += bias[col & 255] + deg * v2[col & 255];
          if (EPI==3) v += (float)gridv[row] * avec[col & 255];
          v = fmaxf(v, 0.f);
        } else if (EPI==2) {
          v += bias[col];
        }
        C[(size_t)row*ldc + col] = (f16)v;
      }
    }
  }
}

// ---- MERGED layer kernel: U_l = relu([U|R]@BtU^T + epi) AND
//      PQ_{l+1} = U_l @ BtPQ^T + pqb  (U never re-read from HBM).
// Phase 1: identical to gemm8 (grid 512 x 1, nbase=0).
// Phase 2: U stashed in LDS (Bs region, 64KB, XOR-swizzled); BtPQ staged in
//          32KB chunks into the As region; acc2 over 2 column-halves.
// EPI as gemm8 (1 or 3) for the U epilogue.
template<int KK, int EPI>
__global__ __launch_bounds__(512) void gemm_merge(
    const f16* __restrict__ A, int lda,
    const f16* __restrict__ BtU_,   // [256][KK] slice, row stride 512
    const f16* __restrict__ BtPQ_,  // [512][256]
    f16* __restrict__ Uo,           // ldc 512, cols 0..255
    f16* __restrict__ PQo,          // [N][512]
    const float* __restrict__ bias,
    const float* __restrict__ v2,
    const float* __restrict__ avec,
    const int* __restrict__ gridv,
    const float* __restrict__ bias2)
{
  constexpr int NT = KK/64;
  __shared__ f16 As[2][128*64];   // 32 KB (phase2: 256x64 chunk)
  __shared__ f16 Bs[2][256*64];   // 64 KB (phase2: U_lds 128x256)
  const int tid  = threadIdx.x;
  const int lane = tid & 63;
  const int w    = tid >> 6;
  const int wm   = w >> 2, wn = w & 3;

  int bid = blockIdx.x;
  bid = (bid & 7) * 64 + (bid >> 3);     // band swizzle (512 blocks)
  const int mbase = bid * 128;

  f32x4 acc[4][4];
#pragma unroll
  for (int a=0;a<4;a++)
#pragma unroll
    for (int b=0;b<4;b++) acc[a][b] = (f32x4){0.f,0.f,0.f,0.f};

  const int r8  = lane >> 3;
  const int c8s = ((lane & 7) ^ r8) * 8;

#define STAGEM(kt, buf)                                                        \
  {                                                                            \
    const f16* Ab = A + (size_t)mbase*lda + (kt)*64;                           \
    _Pragma("unroll")                                                          \
    for (int p=0;p<2;p++) {                                                    \
      int qc = p*8 + w;                                                        \
      gload_lds16(Ab + (size_t)(qc*8 + r8)*lda + c8s, &As[buf][qc*512]);       \
    }                                                                          \
    const f16* Bb = BtU_ + (kt)*64;                                            \
    _Pragma("unroll")                                                          \
    for (int p=0;p<4;p++) {                                                    \
      int qc = p*8 + w;                                                        \
      gload_lds16(Bb + (size_t)(qc*8 + r8)*512 + c8s, &Bs[buf][qc*512]);       \
    }                                                                          \
  }

  STAGEM(0, 0);
  __syncthreads();
  int cur = 0;
  for (int kt = 0; kt < NT; ++kt) {
    if (kt + 1 < NT) STAGEM(kt + 1, cur ^ 1);
    const f16* Acur = &As[cur][0];
    const f16* Bcur = &Bs[cur][0];
#pragma unroll
    for (int ks=0; ks<2; ++ks) {
      const int off = (((ks*4 + (lane>>4)) ^ (lane & 7)) * 8);
      f16x8 af[4], bf[4];
#pragma unroll
      for (int fm=0; fm<4; ++fm)
        af[fm] = *(const f16x8*)&Acur[(wm*64 + fm*16 + (lane&15))*64 + off];
#pragma unroll
      for (int fn=0; fn<4; ++fn)
        bf[fn] = *(const f16x8*)&Bcur[(wn*64 + fn*16 + (lane&15))*64 + off];
#pragma unroll
      for (int fm=0; fm<4; ++fm)
#pragma unroll
        for (int fn=0; fn<4; ++fn)
          acc[fm][fn] = __builtin_amdgcn_mfma_f32_16x16x32_f16(af[fm], bf[fn], acc[fm][fn], 0,0,0);
    }
    __syncthreads();
    cur ^= 1;
  }
#undef STAGEM

  // ---- phase-1 epilogue: U -> global AND swizzled LDS (Bs region) ----
  f16* Ul = &Bs[0][0];   // [128][256] f16, block swizzle blk^(row&7)
#pragma unroll
  for (int fm=0; fm<4; ++fm) {
#pragma unroll
    for (int fn=0; fn<4; ++fn) {
      const int coll = wn*64 + fn*16 + (lane&15);
#pragma unroll
      for (int r=0;r<4;r++) {
        int rl  = wm*64 + (lane>>4)*4 + fm*16 + r;
        int row = mbase + rl;
        float v = acc[fm][fn][r];
        int i = row >> 8, j = row & 255;
        float deg = (float)((i>0)+(i<255)+(j>0)+(j<255));
        v += bias[coll] + deg * v2[coll];
        if (EPI==3) v += (float)gridv[row] * avec[coll];
        v = fmaxf(v, 0.f);
        f16 hv = (f16)v;
        Uo[(size_t)row*512 + coll] = hv;
        int sblk = (coll >> 3) ^ (rl & 7);
        Ul[rl*256 + sblk*8 + (coll & 7)] = hv;
      }
    }
  }
  __syncthreads();

  // ---- phase 2: PQ = U_lds @ BtPQ^T, two 256-col halves ----
  f16* Bc = &As[0][0];   // [256][64] chunk
  for (int h=0; h<2; ++h) {
    f32x4 acc2[4][4];
#pragma unroll
    for (int a=0;a<4;a++)
#pragma unroll
      for (int b=0;b<4;b++) acc2[a][b] = (f32x4){0.f,0.f,0.f,0.f};
    for (int kt=0; kt<4; ++kt) {
      const f16* Bb = BtPQ_ + (size_t)(h*256)*256 + kt*64;
#pragma unroll
      for (int p=0;p<4;p++) {
        int qc = p*8 + w;
        gload_lds16(Bb + (size_t)(qc*8 + r8)*256 + c8s, &Bc[qc*512]);
      }
      __syncthreads();
#pragma unroll
      for (int ks=0; ks<2; ++ks) {
        f16x8 af[4], bf[4];
#pragma unroll
        for (int fm=0; fm<4; ++fm) {
          int rl = wm*64 + fm*16 + (lane&15);
          int sblk = (kt*8 + ks*4 + (lane>>4)) ^ (rl & 7);
          af[fm] = *(const f16x8*)&Ul[rl*256 + sblk*8];
        }
#pragma unroll
        for (int fn=0; fn<4; ++fn) {
          int rb = wn*64 + fn*16 + (lane&15);
          int off = (((ks*4 + (lane>>4)) ^ (rb & 7)) * 8);
          bf[fn] = *(const f16x8*)&Bc[rb*64 + off];
        }
#pragma unroll
        for (int fm=0; fm<4; ++fm)
#pragma unroll
          for (int fn=0; fn<4; ++fn)
            acc2[fm][fn] = __builtin_amdgcn_mfma_f32_16x16x32_f16(af[fm], bf[fn], acc2[fm][fn], 0,0,0);
      }
      __syncthreads();
    }
    const float* b2 = bias2 + h*256;
#pragma unroll
    for (int fm=0; fm<4; ++fm) {
#pragma unroll
      for (int fn=0; fn<4; ++fn) {
        const int coll = wn*64 + fn*16 + (lane&15);
#pragma unroll
        for (int r=0;r<4;r++) {
          int row = mbase + wm*64 + (lane>>4)*4 + fm*16 + r;
          PQo[(size_t)row*512 + h*256 + coll] = (f16)(acc2[fm][fn][r] + b2[coll]);
        }
      }
    }
  }
}

// ---- 4-wave 128x128 GEMM core (K=256), used by the merged fold dispatch ----
__device__ __forceinline__ void gemm_core256(
    const f16* __restrict__ A, int lda,
    const f16* __restrict__ Bt, int ldb,
    f16* __restrict__ C, int ldc,
    int mbase, int nbase, f16* As, f16* Bs)
{
  const int tid  = threadIdx.x;
  const int lane = tid & 63;
  const int w    = tid >> 6;
  const int wm   = w >> 1, wn = w & 1;

  f32x4 acc[4][4];
#pragma unroll
  for (int a=0;a<4;a++)
#pragma unroll
    for (int b=0;b<4;b++) acc[a][b] = (f32x4){0.f,0.f,0.f,0.f};

  const int r8  = lane >> 3;
  const int c8s = ((lane & 7) ^ r8) * 8;

  for (int kt = 0; kt < 4; ++kt) {
    const f16* Ab = A  + (size_t)(mbase + w*32)*lda + kt*64;
    const f16* Bb = Bt + (size_t)(nbase + w*32)*ldb + kt*64;
#pragma unroll
    for (int i=0;i<4;i++) {
      gload_lds16(Ab + (size_t)(i*8 + r8)*lda + c8s, &As[(w*32+i*8)*64]);
      gload_lds16(Bb + (size_t)(i*8 + r8)*ldb + c8s, &Bs[(w*32+i*8)*64]);
    }
    __syncthreads();
#pragma unroll
    for (int ks=0; ks<2; ++ks) {
      const int off = (((ks*4 + (lane>>4)) ^ (lane & 7)) * 8);
      f16x8 af[4], bf[4];
#pragma unroll
      for (int fm=0; fm<4; ++fm)
        af[fm] = *(const f16x8*)&As[(wm*64 + fm*16 + (lane&15))*64 + off];
#pragma unroll
      for (int fn=0; fn<4; ++fn)
        bf[fn] = *(const f16x8*)&Bs[(wn*64 + fn*16 + (lane&15))*64 + off];
#pragma unroll
      for (int fm=0; fm<4; ++fm)
#pragma unroll
        for (int fn=0; fn<4; ++fn)
          acc[fm][fn] = __builtin_amdgcn_mfma_f32_16x16x32_f16(af[fm], bf[fn], acc[fm][fn], 0,0,0);
    }
    __syncthreads();
  }

  const int row0 = mbase + wm*64 + (lane>>4)*4;
  const int col0 = nbase + wn*64 + (lane&15);
#pragma unroll
  for (int fm=0; fm<4; ++fm)
#pragma unroll
    for (int fn=0; fn<4; ++fn)
#pragma unroll
      for (int r=0;r<4;r++)
        C[(size_t)(row0 + fm*16 + r)*ldc + (col0 + fn*16)] = (f16)acc[fm][fn][r];
}

// all 4 weight-fold GEMMs in one dispatch (86 blocks)
__global__ __launch_bounds__(256) void fold_all(
    const f16* __restrict__ BtA,  const f16* __restrict__ uW2h,
    const f16* __restrict__ mW2h, const f16* __restrict__ uW1aT,
    const f16* __restrict__ uW1bT,const f16* __restrict__ oWTh,
    f16* __restrict__ BtPQ, f16* __restrict__ BtU, f16* __restrict__ Wp2t)
{
  __shared__ f16 As[128*64];
  __shared__ f16 Bs[128*64];
  const int b = blockIdx.x;
  if (b < 40) {                 // BtPQ[l] = BtA[l] @ uW2h[l-1]^T, l=z+1
    int z = b >> 3, rem = b & 7, x = rem & 3, y = rem >> 2;
    gemm_core256(BtA + (size_t)(z+1)*131072, 256, uW2h + (size_t)z*65536, 256,
                 BtPQ + (size_t)(z+1)*131072, 256, x*128, y*128, As, Bs);
  } else if (b < 60) {          // BtU[l] 1st half = uW1aT[l] @ uW2h[l-1]^T
    int rem = b - 40, z = rem >> 2, r2 = rem & 3, x = r2 & 1, y = r2 >> 1;
    gemm_core256(uW1aT + (size_t)(z+1)*65536, 256, uW2h + (size_t)z*65536, 256,
                 BtU + (size_t)(z+1)*131072, 512, x*128, y*128, As, Bs);
  } else if (b < 84) {          // BtU[l] 2nd half = uW1bT[l] @ mW2h[l]^T
    int rem = b - 60, z = rem >> 2, r2 = rem & 3, x = r2 & 1, y = r2 >> 1;
    gemm_core256(uW1bT + (size_t)z*65536, 256, mW2h + (size_t)z*65536, 256,
                 BtU + (size_t)z*131072 + 256, 512, x*128, y*128, As, Bs);
  } else {                      // Wp2t = oWTh @ uW2h[5]^T
    int y = b - 84;
    gemm_core256(oWTh, 256, uW2h + (size_t)5*65536, 256,
                 Wp2t, 256, 0, y*128, As, Bs);
  }
}

// R[n] = sum over valid dirs of relu(P[src]+Q[n]+cvec_d+(si/256)*wsi+(sj/256)*wsj)
template<int R1>
__global__ __launch_bounds__(256) void edge_fuse(
    const f16* __restrict__ PQ, f16* __restrict__ UR,
    const float* __restrict__ cvec, const float* __restrict__ wsi_,
    const float* __restrict__ wsj_,
    const int* __restrict__ gridv, const float* __restrict__ pa,
    const float* __restrict__ pc)
{
  const int t  = threadIdx.x;
  const int ln = t >> 5, ch = t & 31;
  int bid = blockIdx.x;
  bid = (bid & 7) * 1024 + (bid >> 3);
  const int n  = bid*8 + ln;
  const int i  = n >> 8, j = n & 255;
  const int co = ch*8;

  float q[8], pa0[8], pc0[8];
  if (R1) {
    float g = (float)gridv[n];
#pragma unroll
    for (int e=0;e<8;e++) {
      pa0[e] = pa[co+e]; pc0[e] = pc[co+e];
      q[e] = g*pa[256+co+e] + pc[256+co+e];
    }
  } else {
    f16x8 qv = *(const f16x8*)&PQ[(size_t)n*512 + 256 + co];
#pragma unroll
    for (int e=0;e<8;e++) q[e] = (float)qv[e];
  }
  float wi[8], wj[8];
#pragma unroll
  for (int e=0;e<8;e++){ wi[e]=wsi_[co+e]; wj[e]=wsj_[co+e]; }
  float acc[8];
#pragma unroll
  for (int e=0;e<8;e++) acc[e]=0.f;

  const int DI[4] = {-1,1,0,0};
  const int DJ[4] = {0,0,-1,1};
#pragma unroll
  for (int d=0; d<4; ++d) {
    int si = i - DI[d], sj = j - DJ[d];
    if (si>=0 && si<HG && sj>=0 && sj<WGD) {
      int s = si*WGD + sj;
      float fsi = si * (1.f/HG), fsj = sj * (1.f/WGD);
      float pvf[8];
      if (R1) {
        float gs = (float)gridv[s];
#pragma unroll
        for (int e=0;e<8;e++) pvf[e] = gs*pa0[e] + pc0[e];
      } else {
        f16x8 pv = *(const f16x8*)&PQ[(size_t)s*512 + co];
#pragma unroll
        for (int e=0;e<8;e++) pvf[e] = (float)pv[e];
      }
#pragma unroll
      for (int e=0;e<8;e++) {
        float v = pvf[e] + q[e] + cvec[d*256+co+e] + fsi*wi[e] + fsj*wj[e];
        acc[e] += fmaxf(v, 0.f);
      }
    }
  }
  f16x8 outv;
#pragma unroll
  for (int e=0;e<8;e++) outv[e] = (f16)acc[e];
  *(f16x8*)&UR[(size_t)n*512 + 256 + co] = outv;
}

// out[n,0..9] = U6[n,:] @ Wp2t^T + ob2  via MFMA, 1 wave = 16 nodes
__global__ __launch_bounds__(256) void out_mfma(
    const f16* __restrict__ U,        // lda 512
    const f16* __restrict__ Wp2t,     // [128][256], rows >=10 zero
    const float* __restrict__ ob2,
    float* __restrict__ out)
{
  int lane = threadIdx.x & 63;
  int wv   = threadIdx.x >> 6;
  int nbase = blockIdx.x*64 + wv*16;
  f32x4 acc = (f32x4){0.f,0.f,0.f,0.f};
  int r  = lane & 15;
  int kg = (lane >> 4) * 8;
  const f16* Up = U + (size_t)(nbase + r)*512 + kg;
  const f16* Bp = Wp2t + r*256 + kg;
#pragma unroll
  for (int kt=0; kt<8; ++kt) {
    f16x8 af = *(const f16x8*)(Up + kt*32);
    f16x8 bf = *(const f16x8*)(Bp + kt*32);
    acc = __builtin_amdgcn_mfma_f32_16x16x32_f16(af, bf, acc, 0,0,0);
  }
  int col = lane & 15;
  int row0 = (lane>>4)*4;
  if (col < 10) {
    float bo = ob2[col];
#pragma unroll
    for (int rr=0; rr<4; ++rr)
      out[(size_t)(nbase + row0 + rr)*10 + col] = acc[rr] + bo;
  }
}

// ---- prep: everything small + all transpose-casts in ONE dispatch ----
__global__ __launch_bounds__(256) void prep_small(
    const float* __restrict__ uW2, const float* __restrict__ mW2,
    const float* __restrict__ oW,  const float* __restrict__ mW1,
    const float* __restrict__ mb1, const float* __restrict__ mb2,
    const float* __restrict__ uW1, const float* __restrict__ ub1,
    const float* __restrict__ ub2, const float* __restrict__ nb,
    const float* __restrict__ nW,  const float* __restrict__ ob,
    f16* __restrict__ uW2h, f16* __restrict__ mW2h, f16* __restrict__ oWTh,
    float* __restrict__ cvec, float* __restrict__ wsi_, float* __restrict__ wsj_,
    float* __restrict__ v2, float* __restrict__ ubias, float* __restrict__ avec,
    float* __restrict__ pqb, float* __restrict__ pa, float* __restrict__ pc,
    float* __restrict__ ob2,
    f16* __restrict__ BtA, f16* __restrict__ uW1aT, f16* __restrict__ uW1bT)
{
  __shared__ float red[3][4][64];
  __shared__ float tbuf[32][33];
  const int b = blockIdx.x;
  const int tid = threadIdx.x;
  if (b < 1536) {
    int idx = b*256 + tid;
    uW2h[idx] = (f16)uW2[idx];
    mW2h[idx] = (f16)mW2[idx];
  } else if (b < 1664) {
    int c = b - 1536, j = tid;
    oWTh[c*256 + j] = (c < 10) ? (f16)oW[j*10 + c] : (f16)0.f;
  } else if (b < 1670) {
    int l = b - 1664, j = tid;
    const float* base = mW1 + (size_t)l*516*256;
    float w512 = base[512*256 + j], w513 = base[513*256 + j];
    float b1 = mb1[l*256 + j];
    const int DI[4] = {-1,1,0,0};
    const int DJ[4] = {0,0,-1,1};
    for (int d=0;d<4;d++)
      cvec[(l*4+d)*256 + j] = (float)DI[d]*w512 + (float)DJ[d]*w513 + b1;
    wsi_[l*256+j] = base[514*256 + j];
    wsj_[l*256+j] = base[515*256 + j];
  } else if (b < 1694) {
    int pr = tid & 63, q = tid >> 6;
    int pair = (b-1670)*64 + pr;
    int l = pair >> 8, j = pair & 255;
    const float* prevb = l ? (ub2 + (l-1)*256) : nb;
    float s1=0.f, s2=0.f, s3=0.f;
    for (int t = q*64; t < q*64+64; ++t) {
      s1 += mb2[l*256+t] * uW1[((size_t)l*512+256+t)*256 + j];
      s2 += prevb[t]     * uW1[((size_t)l*512+t)*256 + j];
      if (l==0) s3 += nW[t] * uW1[(size_t)t*256 + j];
    }
    red[0][q][pr]=s1; red[1][q][pr]=s2; red[2][q][pr]=s3;
    __syncthreads();
    if (q==0) {
      float a = red[0][0][pr]+red[0][1][pr]+red[0][2][pr]+red[0][3][pr];
      float bb = red[1][0][pr]+red[1][1][pr]+red[1][2][pr]+red[1][3][pr];
      v2[pair] = a;
      ubias[pair] = ub1[pair] + bb;
      if (l==0) avec[j] = red[2][0][pr]+red[2][1][pr]+red[2][2][pr]+red[2][3][pr];
    }
  } else if (b < 1742) {
    int pr = tid & 63, q = tid >> 6;
    int pair = (b-1694)*64 + pr;
    int l = pair >> 9, c = pair & 511;
    int rowoff = (c < 256) ? 0 : 256;
    int cc = c & 255;
    const float* base = mW1 + (size_t)l*516*256 + (size_t)rowoff*256 + cc;
    float s1=0.f, s2=0.f;
    if (l==0) {
      for (int j=q*64; j<q*64+64; ++j) { float wv = base[(size_t)j*256]; s1 += nW[j]*wv; s2 += nb[j]*wv; }
    } else {
      const float* pb = ub2 + (l-1)*256;
      for (int j=q*64; j<q*64+64; ++j) s1 += pb[j]*base[(size_t)j*256];
    }
    red[0][q][pr]=s1; red[1][q][pr]=s2;
    __syncthreads();
    if (q==0) {
      float a = red[0][0][pr]+red[0][1][pr]+red[0][2][pr]+red[0][3][pr];
      if (l==0) { pa[c]=a; pc[c]=red[1][0][pr]+red[1][1][pr]+red[1][2][pr]+red[1][3][pr]; }
      else pqb[pair] = a;
    }
  } else if (b == 1742) {
    int c = tid >> 4, jg = tid & 15;
    float s = 0.f;
    if (c < 10)
      for (int j=jg*16; j<jg*16+16; ++j) s += ub2[5*256+j]*oW[j*10+c];
    red[0][c>>2][(c&3)*16+jg] = s;
    __syncthreads();
    if (jg==0 && c < 16) {
      float a=0.f;
      for (int t2=0;t2<16;t2++) a += red[0][c>>2][(c&3)*16+t2];
      ob2[c] = (c < 10) ? a + ob[c] : 0.f;
    }
  } else {
    int t = b - 1743;
    int z = t >> 6, rem = t & 63;
    int bxs = (rem & 7) * 32, bys = (rem >> 3) * 32;
    const int q = z / 6, l = z % 6;
    const float* s;
    f16* d;
    if (q == 0)      { s = mW1 + (size_t)l*516*256;          d = BtA   + (size_t)l*131072; }
    else if (q == 1) { s = mW1 + (size_t)l*516*256 + 65536;  d = BtA   + (size_t)l*131072 + 65536; }
    else if (q == 2) { s = uW1 + (size_t)l*131072;           d = uW1aT + (size_t)l*65536; }
    else             { s = uW1 + (size_t)l*131072 + 65536;   d = uW1bT + (size_t)l*65536; }
    const int tx = tid & 31, ty = tid >> 5;
#pragma unroll
    for (int rr=0; rr<4; ++rr)
      tbuf[ty+rr*8][tx] = s[(size_t)(bys+ty+rr*8)*256 + bxs+tx];
    __syncthreads();
#pragma unroll
    for (int rr=0; rr<4; ++rr)
      d[(size_t)(bxs+ty+rr*8)*256 + bys+tx] = (f16)tbuf[tx][ty+rr*8];
  }
}

extern "C" void kernel_launch(void* const* d_in, const int* in_sizes, int n_in,
                              void* d_out, int out_size, void* d_ws, size_t ws_size,
                              hipStream_t stream)
{
  const int*   gridv = (const int*) d_in[0];
  const float* nW   = (const float*)d_in[3];
  const float* nb   = (const float*)d_in[4];
  const float* mW1  = (const float*)d_in[5];
  const float* mb1  = (const float*)d_in[6];
  const float* mW2  = (const float*)d_in[7];
  const float* mb2  = (const float*)d_in[8];
  const float* uW1  = (const float*)d_in[9];
  const float* ub1  = (const float*)d_in[10];
  const float* uW2  = (const float*)d_in[11];
  const float* ub2  = (const float*)d_in[12];
  const float* oW   = (const float*)d_in[13];
  const float* ob   = (const float*)d_in[14];
  float* out = (float*)d_out;

  char* ws = (char*)d_ws;
  size_t off = 0;
  f16* URa  = (f16*)(ws + off); off += (size_t)NN*512*2;
  f16* URb  = (f16*)(ws + off); off += (size_t)NN*512*2;
  f16* PQ   = (f16*)(ws + off); off += (size_t)NN*512*2;
  f16* BtA  = (f16*)(ws + off); off += 6*512*256*2;
  f16* BtPQ = (f16*)(ws + off); off += 6*512*256*2;   // slot 0 unused
  f16* BtU  = (f16*)(ws + off); off += 6*256*512*2;
  f16* uW2h = (f16*)(ws + off); off += 6*256*256*2;
  f16* mW2h = (f16*)(ws + off); off += 6*256*256*2;
  f16* uW1aT= (f16*)(ws + off); off += 6*256*256*2;
  f16* uW1bT= (f16*)(ws + off); off += 6*256*256*2;
  f16* oWTh = (f16*)(ws + off); off += 128*256*2;
  f16* Wp2t = (f16*)(ws + off); off += 128*256*2;
  float* cvec = (float*)(ws + off); off += 6*4*256*4;
  float* wsi_ = (float*)(ws + off); off += 6*256*4;
  float* wsj_ = (float*)(ws + off); off += 6*256*4;
  float* v2   = (float*)(ws + off); off += 6*256*4;
  float* ubias= (float*)(ws + off); off += 6*256*4;
  float* pqb  = (float*)(ws + off); off += 6*512*4;   // slot 0 unused
  float* pa   = (float*)(ws + off); off += 512*4;
  float* pc   = (float*)(ws + off); off += 512*4;
  float* avec = (float*)(ws + off); off += 256*4;
  float* ob2  = (float*)(ws + off); off += 16*4;

  // ---- prep (2 dispatches) ----
  prep_small<<<3279,256,0,stream>>>(uW2, mW2, oW, mW1, mb1, mb2, uW1, ub1, ub2,
                                    nb, nW, ob,
                                    uW2h, mW2h, oWTh, cvec, wsi_, wsj_,
                                    v2, ubias, avec, pqb, pa, pc, ob2,
                                    BtA, uW1aT, uW1bT);
  fold_all<<<86,256,0,stream>>>(BtA, uW2h, mW2h, uW1aT, uW1bT, oWTh,
                                BtPQ, BtU, Wp2t);

  // ---- layer 1: R_1 analytic, then merged U_1 + PQ_2 ----
  edge_fuse<1><<<8192,256,0,stream>>>(nullptr, URa, cvec, wsi_, wsj_, gridv, pa, pc);
  gemm_merge<256,3><<<512,512,0,stream>>>(
      URa + 256, 512, BtU + 256, BtPQ + (size_t)1*131072,
      URb, PQ, ubias, v2, avec, gridv, pqb + 1*512);

  // ---- layers 2..5: edge_fuse + merged(U_l + PQ_{l+1}) ----
  f16* cur = URb; f16* nxt = URa;
  for (int l=1;l<5;l++){
    edge_fuse<0><<<8192,256,0,stream>>>(PQ, cur, cvec + l*1024, wsi_ + l*256, wsj_ + l*256,
                                        nullptr, nullptr, nullptr);
    gemm_merge<512,1><<<512,512,0,stream>>>(
        cur, 512, BtU + (size_t)l*131072, BtPQ + (size_t)(l+1)*131072,
        nxt, PQ, ubias + l*256, v2 + l*256, nullptr, nullptr, pqb + (l+1)*512);
    f16* t = cur; cur = nxt; nxt = t;
  }

  // ---- layer 6: edge_fuse + plain update GEMM ----
  edge_fuse<0><<<8192,256,0,stream>>>(PQ, cur, cvec + 5*1024, wsi_ + 5*256, wsj_ + 5*256,
                                      nullptr, nullptr, nullptr);
  gemm8<512,1><<<dim3(512,1),512,0,stream>>>(
      cur, 512, BtU + (size_t)5*131072, 512, nxt, 512,
      ubias + 5*256, v2 + 5*256, nullptr, nullptr);

  // out = U6 @ Wp2t^T + ob2
  out_mfma<<<1024,256,0,stream>>>(nxt, Wp2t, ob2, out);
}

// Round 10
// 449.930 us; speedup vs baseline: 1.4696x; 1.0820x over previous
//
#include <hip/hip_runtime.h>

#define HG 256
#define WGD 256
#define NN (HG*WGD)
#define NL 6

typedef _Float16 f16;
typedef _Float16 f16x8 __attribute__((ext_vector_type(8)));
typedef float f32x4 __attribute__((ext_vector_type(4)));

__device__ __forceinline__ void gload_lds16(const f16* g, f16* lds) {
  __builtin_amdgcn_global_load_lds(
      (const __attribute__((address_space(1))) unsigned int*)g,
      (__attribute__((address_space(3))) unsigned int*)lds, 16, 0, 0);
}

// ---- MERGED layer kernel, BM=64, 80KB LDS -> 2 blocks/CU ----
// Phase 1: U_l[64x256] = relu([U|R]@BtU^T + epi)  (K=KK, dbuf 2-phase pipeline)
// Phase 2 (DOPQ): PQ_{l+1}[64x512] = U_lds @ BtPQ^T + pqb  (U stays in LDS)
// LDS arena (f16 elems): phase1 As0[0,4096) As1[4096,8192) Bs0[8192,24576)
// Bs1[24576,40960); phase2 Ul[0,16384) Bc[16384,32768).
// 8 waves, all covering rows 0..63; wave w owns cols w*32..w*32+32.
// EPI: 1 +bias+deg*v2, relu | 3 EPI1 + g*avec (layer-1)
template<int KK, int EPI, int DOPQ>
__global__ __launch_bounds__(512,4) void gemm_merge(
    const f16* __restrict__ A, int lda,
    const f16* __restrict__ BtU_,   // [256][KK] slice, row stride 512
    const f16* __restrict__ BtPQ_,  // [512][256]
    f16* __restrict__ Uo,           // ldc 512, cols 0..255
    f16* __restrict__ PQo,          // [N][512]
    const float* __restrict__ bias,
    const float* __restrict__ v2,
    const float* __restrict__ avec,
    const int* __restrict__ gridv,
    const float* __restrict__ bias2)
{
  constexpr int NT = KK/64;
  __shared__ f16 sh[40960];   // 80 KB
  const int tid  = threadIdx.x;
  const int lane = tid & 63;
  const int w    = tid >> 6;          // 0..7 (N-wave)

  int bid = blockIdx.x;
  bid = (bid & 7) * 128 + (bid >> 3);   // band swizzle (1024 blocks)
  const int mbase = bid * 64;

  f32x4 acc[4][2];
#pragma unroll
  for (int a=0;a<4;a++)
#pragma unroll
    for (int b=0;b<2;b++) acc[a][b] = (f32x4){0.f,0.f,0.f,0.f};

  const int r8  = lane >> 3;                 // 0..7
  const int c8s = ((lane & 7) ^ r8) * 8;     // pre-swizzled src col (f16)

#define ASB(b) (sh + (b)*4096)
#define BSB(b) (sh + 8192 + (b)*16384)
#define UL (sh)
#define BC (sh + 16384)

#define STAGEM(kt, buf)                                                        \
  {                                                                            \
    gload_lds16(A + (size_t)(mbase + w*8 + r8)*lda + (kt)*64 + c8s,            \
                ASB(buf) + w*512);                                             \
    const f16* Bb = BtU_ + (kt)*64;                                            \
    _Pragma("unroll")                                                          \
    for (int p=0;p<4;p++) {                                                    \
      int qc = p*8 + w;                                                        \
      gload_lds16(Bb + (size_t)(qc*8 + r8)*512 + c8s, BSB(buf) + qc*512);      \
    }                                                                          \
  }

  STAGEM(0, 0);
  __syncthreads();
  int cur = 0;
  for (int kt = 0; kt < NT; ++kt) {
    if (kt + 1 < NT) STAGEM(kt + 1, cur ^ 1);
    const f16* Acur = ASB(cur);
    const f16* Bcur = BSB(cur);
#pragma unroll
    for (int ks=0; ks<2; ++ks) {
      const int off = (((ks*4 + (lane>>4)) ^ (lane & 7)) * 8);
      f16x8 af[4], bf[2];
#pragma unroll
      for (int fm=0; fm<4; ++fm)
        af[fm] = *(const f16x8*)&Acur[(fm*16 + (lane&15))*64 + off];
#pragma unroll
      for (int fn=0; fn<2; ++fn)
        bf[fn] = *(const f16x8*)&Bcur[(w*32 + fn*16 + (lane&15))*64 + off];
#pragma unroll
      for (int fm=0; fm<4; ++fm)
#pragma unroll
        for (int fn=0; fn<2; ++fn)
          acc[fm][fn] = __builtin_amdgcn_mfma_f32_16x16x32_f16(af[fm], bf[fn], acc[fm][fn], 0,0,0);
    }
    __syncthreads();
    cur ^= 1;
  }
#undef STAGEM

  // ---- phase-1 epilogue: U -> global AND swizzled LDS (Ul) ----
#pragma unroll
  for (int fm=0; fm<4; ++fm) {
#pragma unroll
    for (int fn=0; fn<2; ++fn) {
      const int coll = w*32 + fn*16 + (lane&15);
#pragma unroll
      for (int r=0;r<4;r++) {
        int rl  = fm*16 + (lane>>4)*4 + r;
        int row = mbase + rl;
        float v = acc[fm][fn][r];
        int i = row >> 8, j = row & 255;
        float deg = (float)((i>0)+(i<255)+(j>0)+(j<255));
        v += bias[coll] + deg * v2[coll];
        if (EPI==3) v += (float)gridv[row] * avec[coll];
        v = fmaxf(v, 0.f);
        f16 hv = (f16)v;
        Uo[(size_t)row*512 + coll] = hv;
        if (DOPQ) {
          int sblk = (coll >> 3) ^ (rl & 7);
          UL[rl*256 + sblk*8 + (coll & 7)] = hv;
        }
      }
    }
  }

  if (DOPQ) {
    __syncthreads();
    // ---- phase 2: PQ = U_lds @ BtPQ^T, two 256-col halves ----
    for (int h=0; h<2; ++h) {
      f32x4 acc2[4][2];
#pragma unroll
      for (int a=0;a<4;a++)
#pragma unroll
        for (int b=0;b<2;b++) acc2[a][b] = (f32x4){0.f,0.f,0.f,0.f};
      for (int kt=0; kt<4; ++kt) {
        const f16* Bb = BtPQ_ + (size_t)(h*256)*256 + kt*64;
#pragma unroll
        for (int p=0;p<4;p++) {
          int qc = p*8 + w;
          gload_lds16(Bb + (size_t)(qc*8 + r8)*256 + c8s, BC + qc*512);
        }
        __syncthreads();
#pragma unroll
        for (int ks=0; ks<2; ++ks) {
          f16x8 af[4], bf[2];
#pragma unroll
          for (int fm=0; fm<4; ++fm) {
            int rl = fm*16 + (lane&15);
            int sblk = (kt*8 + ks*4 + (lane>>4)) ^ (rl & 7);
            af[fm] = *(const f16x8*)&UL[rl*256 + sblk*8];
          }
#pragma unroll
          for (int fn=0; fn<2; ++fn) {
            int rb = w*32 + fn*16 + (lane&15);
            int offb = (((ks*4 + (lane>>4)) ^ (rb & 7)) * 8);
            bf[fn] = *(const f16x8*)&BC[rb*64 + offb];
          }
#pragma unroll
          for (int fm=0; fm<4; ++fm)
#pragma unroll
            for (int fn=0; fn<2; ++fn)
              acc2[fm][fn] = __builtin_amdgcn_mfma_f32_16x16x32_f16(af[fm], bf[fn], acc2[fm][fn], 0,0,0);
        }
        __syncthreads();
      }
      const float* b2 = bias2 + h*256;
#pragma unroll
      for (int fm=0; fm<4; ++fm) {
#pragma unroll
        for (int fn=0; fn<2; ++fn) {
          const int coll = w*32 + fn*16 + (lane&15);
#pragma unroll
          for (int r=0;r<4;r++) {
            int row = mbase + fm*16 + (lane>>4)*4 + r;
            PQo[(size_t)row*512 + h*256 + coll] = (f16)(acc2[fm][fn][r] + b2[coll]);
          }
        }
      }
    }
  }
#undef ASB
#undef BSB
#undef UL
#undef BC
}

// ---- 4-wave 128x128 GEMM core (K=256), used by the merged fold dispatch ----
__device__ __forceinline__ void gemm_core256(
    const f16* __restrict__ A, int lda,
    const f16* __restrict__ Bt, int ldb,
    f16* __restrict__ C, int ldc,
    int mbase, int nbase, f16* As, f16* Bs)
{
  const int tid  = threadIdx.x;
  const int lane = tid & 63;
  const int w    = tid >> 6;
  const int wm   = w >> 1, wn = w & 1;

  f32x4 acc[4][4];
#pragma unroll
  for (int a=0;a<4;a++)
#pragma unroll
    for (int b=0;b<4;b++) acc[a][b] = (f32x4){0.f,0.f,0.f,0.f};

  const int r8  = lane >> 3;
  const int c8s = ((lane & 7) ^ r8) * 8;

  for (int kt = 0; kt < 4; ++kt) {
    const f16* Ab = A  + (size_t)(mbase + w*32)*lda + kt*64;
    const f16* Bb = Bt + (size_t)(nbase + w*32)*ldb + kt*64;
#pragma unroll
    for (int i=0;i<4;i++) {
      gload_lds16(Ab + (size_t)(i*8 + r8)*lda + c8s, &As[(w*32+i*8)*64]);
      gload_lds16(Bb + (size_t)(i*8 + r8)*ldb + c8s, &Bs[(w*32+i*8)*64]);
    }
    __syncthreads();
#pragma unroll
    for (int ks=0; ks<2; ++ks) {
      const int off = (((ks*4 + (lane>>4)) ^ (lane & 7)) * 8);
      f16x8 af[4], bf[4];
#pragma unroll
      for (int fm=0; fm<4; ++fm)
        af[fm] = *(const f16x8*)&As[(wm*64 + fm*16 + (lane&15))*64 + off];
#pragma unroll
      for (int fn=0; fn<4; ++fn)
        bf[fn] = *(const f16x8*)&Bs[(wn*64 + fn*16 + (lane&15))*64 + off];
#pragma unroll
      for (int fm=0; fm<4; ++fm)
#pragma unroll
        for (int fn=0; fn<4; ++fn)
          acc[fm][fn] = __builtin_amdgcn_mfma_f32_16x16x32_f16(af[fm], bf[fn], acc[fm][fn], 0,0,0);
    }
    __syncthreads();
  }

  const int row0 = mbase + wm*64 + (lane>>4)*4;
  const int col0 = nbase + wn*64 + (lane&15);
#pragma unroll
  for (int fm=0; fm<4; ++fm)
#pragma unroll
    for (int fn=0; fn<4; ++fn)
#pragma unroll
      for (int r=0;r<4;r++)
        C[(size_t)(row0 + fm*16 + r)*ldc + (col0 + fn*16)] = (f16)acc[fm][fn][r];
}

// all 4 weight-fold GEMMs in one dispatch (86 blocks)
__global__ __launch_bounds__(256) void fold_all(
    const f16* __restrict__ BtA,  const f16* __restrict__ uW2h,
    const f16* __restrict__ mW2h, const f16* __restrict__ uW1aT,
    const f16* __restrict__ uW1bT,const f16* __restrict__ oWTh,
    f16* __restrict__ BtPQ, f16* __restrict__ BtU, f16* __restrict__ Wp2t)
{
  __shared__ f16 As[128*64];
  __shared__ f16 Bs[128*64];
  const int b = blockIdx.x;
  if (b < 40) {
    int z = b >> 3, rem = b & 7, x = rem & 3, y = rem >> 2;
    gemm_core256(BtA + (size_t)(z+1)*131072, 256, uW2h + (size_t)z*65536, 256,
                 BtPQ + (size_t)(z+1)*131072, 256, x*128, y*128, As, Bs);
  } else if (b < 60) {
    int rem = b - 40, z = rem >> 2, r2 = rem & 3, x = r2 & 1, y = r2 >> 1;
    gemm_core256(uW1aT + (size_t)(z+1)*65536, 256, uW2h + (size_t)z*65536, 256,
                 BtU + (size_t)(z+1)*131072, 512, x*128, y*128, As, Bs);
  } else if (b < 84) {
    int rem = b - 60, z = rem >> 2, r2 = rem & 3, x = r2 & 1, y = r2 >> 1;
    gemm_core256(uW1bT + (size_t)z*65536, 256, mW2h + (size_t)z*65536, 256,
                 BtU + (size_t)z*131072 + 256, 512, x*128, y*128, As, Bs);
  } else {
    int y = b - 84;
    gemm_core256(oWTh, 256, uW2h + (size_t)5*65536, 256,
                 Wp2t, 256, 0, y*128, As, Bs);
  }
}

// R[n] = sum over valid dirs of relu(P[src]+Q[n]+cvec_d+(si/256)*wsi+(sj/256)*wsj)
template<int R1>
__global__ __launch_bounds__(256) void edge_fuse(
    const f16* __restrict__ PQ, f16* __restrict__ UR,
    const float* __restrict__ cvec, const float* __restrict__ wsi_,
    const float* __restrict__ wsj_,
    const int* __restrict__ gridv, const float* __restrict__ pa,
    const float* __restrict__ pc)
{
  const int t  = threadIdx.x;
  const int ln = t >> 5, ch = t & 31;
  int bid = blockIdx.x;
  bid = (bid & 7) * 1024 + (bid >> 3);
  const int n  = bid*8 + ln;
  const int i  = n >> 8, j = n & 255;
  const int co = ch*8;

  float q[8], pa0[8], pc0[8];
  if (R1) {
    float g = (float)gridv[n];
#pragma unroll
    for (int e=0;e<8;e++) {
      pa0[e] = pa[co+e]; pc0[e] = pc[co+e];
      q[e] = g*pa[256+co+e] + pc[256+co+e];
    }
  } else {
    f16x8 qv = *(const f16x8*)&PQ[(size_t)n*512 + 256 + co];
#pragma unroll
    for (int e=0;e<8;e++) q[e] = (float)qv[e];
  }
  float wi[8], wj[8];
#pragma unroll
  for (int e=0;e<8;e++){ wi[e]=wsi_[co+e]; wj[e]=wsj_[co+e]; }
  float acc[8];
#pragma unroll
  for (int e=0;e<8;e++) acc[e]=0.f;

  const int DI[4] = {-1,1,0,0};
  const int DJ[4] = {0,0,-1,1};
#pragma unroll
  for (int d=0; d<4; ++d) {
    int si = i - DI[d], sj = j - DJ[d];
    if (si>=0 && si<HG && sj>=0 && sj<WGD) {
      int s = si*WGD + sj;
      float fsi = si * (1.f/HG), fsj = sj * (1.f/WGD);
      float pvf[8];
      if (R1) {
        float gs = (float)gridv[s];
#pragma unroll
        for (int e=0;e<8;e++) pvf[e] = gs*pa0[e] + pc0[e];
      } else {
        f16x8 pv = *(const f16x8*)&PQ[(size_t)s*512 + co];
#pragma unroll
        for (int e=0;e<8;e++) pvf[e] = (float)pv[e];
      }
#pragma unroll
      for (int e=0;e<8;e++) {
        float v = pvf[e] + q[e] + cvec[d*256+co+e] + fsi*wi[e] + fsj*wj[e];
        acc[e] += fmaxf(v, 0.f);
      }
    }
  }
  f16x8 outv;
#pragma unroll
  for (int e=0;e<8;e++) outv[e] = (f16)acc[e];
  *(f16x8*)&UR[(size_t)n*512 + 256 + co] = outv;
}

// out[n,0..9] = U6[n,:] @ Wp2t^T + ob2  via MFMA, 1 wave = 16 nodes
__global__ __launch_bounds__(256) void out_mfma(
    const f16* __restrict__ U,        // lda 512
    const f16* __restrict__ Wp2t,     // [128][256], rows >=10 zero
    const float* __restrict__ ob2,
    float* __restrict__ out)
{
  int lane = threadIdx.x & 63;
  int wv   = threadIdx.x >> 6;
  int nbase = blockIdx.x*64 + wv*16;
  f32x4 acc = (f32x4){0.f,0.f,0.f,0.f};
  int r  = lane & 15;
  int kg = (lane >> 4) * 8;
  const f16* Up = U + (size_t)(nbase + r)*512 + kg;
  const f16* Bp = Wp2t + r*256 + kg;
#pragma unroll
  for (int kt=0; kt<8; ++kt) {
    f16x8 af = *(const f16x8*)(Up + kt*32);
    f16x8 bf = *(const f16x8*)(Bp + kt*32);
    acc = __builtin_amdgcn_mfma_f32_16x16x32_f16(af, bf, acc, 0,0,0);
  }
  int col = lane & 15;
  int row0 = (lane>>4)*4;
  if (col < 10) {
    float bo = ob2[col];
#pragma unroll
    for (int rr=0; rr<4; ++rr)
      out[(size_t)(nbase + row0 + rr)*10 + col] = acc[rr] + bo;
  }
}

// ---- prep: everything small + all transpose-casts in ONE dispatch ----
__global__ __launch_bounds__(256) void prep_small(
    const float* __restrict__ uW2, const float* __restrict__ mW2,
    const float* __restrict__ oW,  const float* __restrict__ mW1,
    const float* __restrict__ mb1, const float* __restrict__ mb2,
    const float* __restrict__ uW1, const float* __restrict__ ub1,
    const float* __restrict__ ub2, const float* __restrict__ nb,
    const float* __restrict__ nW,  const float* __restrict__ ob,
    f16* __restrict__ uW2h, f16* __restrict__ mW2h, f16* __restrict__ oWTh,
    float* __restrict__ cvec, float* __restrict__ wsi_, float* __restrict__ wsj_,
    float* __restrict__ v2, float* __restrict__ ubias, float* __restrict__ avec,
    float* __restrict__ pqb, float* __restrict__ pa, float* __restrict__ pc,
    float* __restrict__ ob2,
    f16* __restrict__ BtA, f16* __restrict__ uW1aT, f16* __restrict__ uW1bT)
{
  __shared__ float red[3][4][64];
  __shared__ float tbuf[32][33];
  const int b = blockIdx.x;
  const int tid = threadIdx.x;
  if (b < 1536) {
    int idx = b*256 + tid;
    uW2h[idx] = (f16)uW2[idx];
    mW2h[idx] = (f16)mW2[idx];
  } else if (b < 1664) {
    int c = b - 1536, j = tid;
    oWTh[c*256 + j] = (c < 10) ? (f16)oW[j*10 + c] : (f16)0.f;
  } else if (b < 1670) {
    int l = b - 1664, j = tid;
    const float* base = mW1 + (size_t)l*516*256;
    float w512 = base[512*256 + j], w513 = base[513*256 + j];
    float b1 = mb1[l*256 + j];
    const int DI[4] = {-1,1,0,0};
    const int DJ[4] = {0,0,-1,1};
    for (int d=0;d<4;d++)
      cvec[(l*4+d)*256 + j] = (float)DI[d]*w512 + (float)DJ[d]*w513 + b1;
    wsi_[l*256+j] = base[514*256 + j];
    wsj_[l*256+j] = base[515*256 + j];
  } else if (b < 1694) {
    int pr = tid & 63, q = tid >> 6;
    int pair = (b-1670)*64 + pr;
    int l = pair >> 8, j = pair & 255;
    const float* prevb = l ? (ub2 + (l-1)*256) : nb;
    float s1=0.f, s2=0.f, s3=0.f;
    for (int t = q*64; t < q*64+64; ++t) {
      s1 += mb2[l*256+t] * uW1[((size_t)l*512+256+t)*256 + j];
      s2 += prevb[t]     * uW1[((size_t)l*512+t)*256 + j];
      if (l==0) s3 += nW[t] * uW1[(size_t)t*256 + j];
    }
    red[0][q][pr]=s1; red[1][q][pr]=s2; red[2][q][pr]=s3;
    __syncthreads();
    if (q==0) {
      float a = red[0][0][pr]+red[0][1][pr]+red[0][2][pr]+red[0][3][pr];
      float bb = red[1][0][pr]+red[1][1][pr]+red[1][2][pr]+red[1][3][pr];
      v2[pair] = a;
      ubias[pair] = ub1[pair] + bb;
      if (l==0) avec[j] = red[2][0][pr]+red[2][1][pr]+red[2][2][pr]+red[2][3][pr];
    }
  } else if (b < 1742) {
    int pr = tid & 63, q = tid >> 6;
    int pair = (b-1694)*64 + pr;
    int l = pair >> 9, c = pair & 511;
    int rowoff = (c < 256) ? 0 : 256;
    int cc = c & 255;
    const float* base = mW1 + (size_t)l*516*256 + (size_t)rowoff*256 + cc;
    float s1=0.f, s2=0.f;
    if (l==0) {
      for (int j=q*64; j<q*64+64; ++j) { float wv = base[(size_t)j*256]; s1 += nW[j]*wv; s2 += nb[j]*wv; }
    } else {
      const float* pb = ub2 + (l-1)*256;
      for (int j=q*64; j<q*64+64; ++j) s1 += pb[j]*base[(size_t)j*256];
    }
    red[0][q][pr]=s1; red[1][q][pr]=s2;
    __syncthreads();
    if (q==0) {
      float a = red[0][0][pr]+red[0][1][pr]+red[0][2][pr]+red[0][3][pr];
      if (l==0) { pa[c]=a; pc[c]=red[1][0][pr]+red[1][1][pr]+red[1][2][pr]+red[1][3][pr]; }
      else pqb[pair] = a;
    }
  } else if (b == 1742) {
    int c = tid >> 4, jg = tid & 15;
    float s = 0.f;
    if (c < 10)
      for (int j=jg*16; j<jg*16+16; ++j) s += ub2[5*256+j]*oW[j*10+c];
    red[0][c>>2][(c&3)*16+jg] = s;
    __syncthreads();
    if (jg==0 && c < 16) {
      float a=0.f;
      for (int t2=0;t2<16;t2++) a += red[0][c>>2][(c&3)*16+t2];
      ob2[c] = (c < 10) ? a + ob[c] : 0.f;
    }
  } else {
    int t = b - 1743;
    int z = t >> 6, rem = t & 63;
    int bxs = (rem & 7) * 32, bys = (rem >> 3) * 32;
    const int q = z / 6, l = z % 6;
    const float* s;
    f16* d;
    if (q == 0)      { s = mW1 + (size_t)l*516*256;          d = BtA   + (size_t)l*131072; }
    else if (q == 1) { s = mW1 + (size_t)l*516*256 + 65536;  d = BtA   + (size_t)l*131072 + 65536; }
    else if (q == 2) { s = uW1 + (size_t)l*131072;           d = uW1aT + (size_t)l*65536; }
    else             { s = uW1 + (size_t)l*131072 + 65536;   d = uW1bT + (size_t)l*65536; }
    const int tx = tid & 31, ty = tid >> 5;
#pragma unroll
    for (int rr=0; rr<4; ++rr)
      tbuf[ty+rr*8][tx] = s[(size_t)(bys+ty+rr*8)*256 + bxs+tx];
    __syncthreads();
#pragma unroll
    for (int rr=0; rr<4; ++rr)
      d[(size_t)(bxs+ty+rr*8)*256 + bys+tx] = (f16)tbuf[tx][ty+rr*8];
  }
}

extern "C" void kernel_launch(void* const* d_in, const int* in_sizes, int n_in,
                              void* d_out, int out_size, void* d_ws, size_t ws_size,
                              hipStream_t stream)
{
  const int*   gridv = (const int*) d_in[0];
  const float* nW   = (const float*)d_in[3];
  const float* nb   = (const float*)d_in[4];
  const float* mW1  = (const float*)d_in[5];
  const float* mb1  = (const float*)d_in[6];
  const float* mW2  = (const float*)d_in[7];
  const float* mb2  = (const float*)d_in[8];
  const float* uW1  = (const float*)d_in[9];
  const float* ub1  = (const float*)d_in[10];
  const float* uW2  = (const float*)d_in[11];
  const float* ub2  = (const float*)d_in[12];
  const float* oW   = (const float*)d_in[13];
  const float* ob   = (const float*)d_in[14];
  float* out = (float*)d_out;

  char* ws = (char*)d_ws;
  size_t off = 0;
  f16* URa  = (f16*)(ws + off); off += (size_t)NN*512*2;
  f16* URb  = (f16*)(ws + off); off += (size_t)NN*512*2;
  f16* PQ   = (f16*)(ws + off); off += (size_t)NN*512*2;
  f16* BtA  = (f16*)(ws + off); off += 6*512*256*2;
  f16* BtPQ = (f16*)(ws + off); off += 6*512*256*2;   // slot 0 unused
  f16* BtU  = (f16*)(ws + off); off += 6*256*512*2;
  f16* uW2h = (f16*)(ws + off); off += 6*256*256*2;
  f16* mW2h = (f16*)(ws + off); off += 6*256*256*2;
  f16* uW1aT= (f16*)(ws + off); off += 6*256*256*2;
  f16* uW1bT= (f16*)(ws + off); off += 6*256*256*2;
  f16* oWTh = (f16*)(ws + off); off += 128*256*2;
  f16* Wp2t = (f16*)(ws + off); off += 128*256*2;
  float* cvec = (float*)(ws + off); off += 6*4*256*4;
  float* wsi_ = (float*)(ws + off); off += 6*256*4;
  float* wsj_ = (float*)(ws + off); off += 6*256*4;
  float* v2   = (float*)(ws + off); off += 6*256*4;
  float* ubias= (float*)(ws + off); off += 6*256*4;
  float* pqb  = (float*)(ws + off); off += 6*512*4;   // slot 0 unused
  float* pa   = (float*)(ws + off); off += 512*4;
  float* pc   = (float*)(ws + off); off += 512*4;
  float* avec = (float*)(ws + off); off += 256*4;
  float* ob2  = (float*)(ws + off); off += 16*4;

  // ---- prep (2 dispatches) ----
  prep_small<<<3279,256,0,stream>>>(uW2, mW2, oW, mW1, mb1, mb2, uW1, ub1, ub2,
                                    nb, nW, ob,
                                    uW2h, mW2h, oWTh, cvec, wsi_, wsj_,
                                    v2, ubias, avec, pqb, pa, pc, ob2,
                                    BtA, uW1aT, uW1bT);
  fold_all<<<86,256,0,stream>>>(BtA, uW2h, mW2h, uW1aT, uW1bT, oWTh,
                                BtPQ, BtU, Wp2t);

  // ---- layer 1: R_1 analytic, then merged U_1 + PQ_2 ----
  edge_fuse<1><<<8192,256,0,stream>>>(nullptr, URa, cvec, wsi_, wsj_, gridv, pa, pc);
  gemm_merge<256,3,1><<<1024,512,0,stream>>>(
      URa + 256, 512, BtU + 256, BtPQ + (size_t)1*131072,
      URb, PQ, ubias, v2, avec, gridv, pqb + 1*512);

  // ---- layers 2..5: edge_fuse + merged(U_l + PQ_{l+1}) ----
  f16* cur = URb; f16* nxt = URa;
  for (int l=1;l<5;l++){
    edge_fuse<0><<<8192,256,0,stream>>>(PQ, cur, cvec + l*1024, wsi_ + l*256, wsj_ + l*256,
                                        nullptr, nullptr, nullptr);
    gemm_merge<512,1,1><<<1024,512,0,stream>>>(
        cur, 512, BtU + (size_t)l*131072, BtPQ + (size_t)(l+1)*131072,
        nxt, PQ, ubias + l*256, v2 + l*256, nullptr, nullptr, pqb + (l+1)*512);
    f16* t = cur; cur = nxt; nxt = t;
  }

  // ---- layer 6: edge_fuse + merged update (no PQ phase) ----
  edge_fuse<0><<<8192,256,0,stream>>>(PQ, cur, cvec + 5*1024, wsi_ + 5*256, wsj_ + 5*256,
                                      nullptr, nullptr, nullptr);
  gemm_merge<512,1,0><<<1024,512,0,stream>>>(
      cur, 512, BtU + (size_t)5*131072, nullptr,
      nxt, nullptr, ubias + 5*256, v2 + 5*256, nullptr, nullptr, nullptr);

  // out = U6 @ Wp2t^T + ob2
  out_mfma<<<1024,256,0,stream>>>(nxt, Wp2t, ob2, out);
}